// Round 7
// baseline (253.449 us; speedup 1.0000x reference)
//
#include <hip/hip_runtime.h>

// GlobalChannelAttention: B=16, C=256, H*W=4096
//
// Pipeline (TN-form GEMMs: C[M,N] = sum_k A[m][k]*B[n][k], K contiguous):
//   1. prep_w: w1 -> W1Th (bf16 transposed), w2/w3 -> hi/lo bf16
//   2. gram: G[b] = X X^T from raw x f32 (hi/lo split in LDS staging),
//      one 512-thr block per (batch, n-split/16), full 256x256 tile,
//      double-buffered LDS, epilogue = f32 ATOMIC adds into Gf (4 MB,
//      memory-side) -- no 64MB partial round-trip. xsum folded in.
//   3. split_g: Gf -> Gh/Gl bf16. T3 = W3*G (G symmetric), Lt = T3*W2^T
//      == logits TRANSPOSED (Lt[d][a]); 64x64 tiles, 256-block grids.
//   4. global softmax: pass1 block partials; pass3 combine + write WT bf16
//      + fused bb[d] = sum_c WT[d][c]*b1[c] (segmented lane reduce).
//   5. Mh = WT*W1T (bf16); out = Mh*X^T + bb with B straight from x f32,
//      in-LDS transpose (pair-packed b32, XOR swizzle); 256x128 blocks so
//      x is fetched exactly once.
//
// Precision: logit chain bf16 hi/lo x3 (err ~2^-17 rel); out chain plain bf16.

typedef unsigned short u16;
typedef __attribute__((ext_vector_type(8))) short short8;
typedef __attribute__((ext_vector_type(4))) float floatx4;

__device__ __forceinline__ u16 f2b(float f) {
  union { float f; unsigned int u; } v; v.f = f;
  unsigned int u = v.u;
  return (u16)((u + 0x7fffu + ((u >> 16) & 1u)) >> 16);  // RNE
}
__device__ __forceinline__ float b2f(u16 h) {
  union { unsigned int u; float f; } v; v.u = ((unsigned int)h) << 16;
  return v.f;
}

// ---------------- merged W prep: transpose w1 + split w2/w3 ----------------
__global__ __launch_bounds__(256) void prep_w_kernel(
    const float* __restrict__ w1, const float* __restrict__ w2, const float* __restrict__ w3,
    u16* __restrict__ W1Th, u16* __restrict__ W2h, u16* __restrict__ W2l,
    u16* __restrict__ W3h, u16* __restrict__ W3l) {
  const int blk = blockIdx.x, t = threadIdx.x;
  if (blk < 64) {  // W1Th[e][c] = w1[c][e]
    __shared__ float tile[32][33];
    const int e0 = (blk & 7) * 32, c0 = (blk >> 3) * 32;
    const int tx = t & 31, ty = t >> 5;
#pragma unroll
    for (int i = 0; i < 4; ++i)
      tile[ty + i * 8][tx] = w1[(c0 + ty + i * 8) * 256 + e0 + tx];
    __syncthreads();
#pragma unroll
    for (int i = 0; i < 4; ++i)
      W1Th[(e0 + ty + i * 8) * 256 + c0 + tx] = f2b(tile[tx][ty + i * 8]);
  } else {
    const int i = (blk - 64) * 256 + t;  // 0..131071
    const int e = i & 0xffff;
    const float f = (i >> 16) ? w3[e] : w2[e];
    u16 h = f2b(f);
    if (i >> 16) { W3h[e] = h; W3l[e] = f2b(f - b2f(h)); }
    else         { W2h[e] = h; W2l[e] = f2b(f - b2f(h)); }
  }
}

// ---- stage 8 f32 -> hi/lo bf16 LDS (one uint4 each) + running sum --------
__device__ __forceinline__ void stage8(const float4 a, const float4 b,
                                       u16* dH, u16* dL, float& xa) {
  const float f[8] = {a.x, a.y, a.z, a.w, b.x, b.y, b.z, b.w};
  union { u16 h8[8]; uint4 q; } uh, ul;
#pragma unroll
  for (int i = 0; i < 8; ++i) {
    const u16 hi = f2b(f[i]);
    uh.h8[i] = hi;
    ul.h8[i] = f2b(f[i] - b2f(hi));
    xa += f[i];
  }
  *(uint4*)dH = uh.q;
  *(uint4*)dL = ul.q;
}

// ---------------- Gram from raw x: full 256x256 per (batch, split) ---------
// 512 threads / 8 waves; wave (wm in {0,128}, wn in {0,64,128,192}) does 128x64.
// Double-buffered LDS; epilogue: atomic f32 adds into Gf (device scope).
__global__ __launch_bounds__(512, 2) void gram_kernel(
    const float* __restrict__ x, float* __restrict__ Gf, float* __restrict__ xsum) {
  constexpr int LR = 40;  // +8 pad: 2-way bank aliasing only (free per m136)
  __shared__ u16 lH[2][256 * LR], lL[2][256 * LR];  // 80 KB total
  const int b = blockIdx.x >> 4, s = blockIdx.x & 15;
  const float* Xb = x + (long)b * 1048576 + s * 256;
  const int t = threadIdx.x;
  const int lane = t & 63, wave = t >> 6;
  const int quad = lane >> 4, l16 = lane & 15;
  const int wm = (wave & 1) * 128, wn = (wave >> 1) * 64;
  const int r0 = t >> 2, qc = (t & 3) * 8;
  const int r1 = r0 + 128;
  floatx4 acc[8][4] = {};
  float xa0 = 0.f, xa1 = 0.f;
  float4 p[4];
  p[0] = *(const float4*)(Xb + (long)r0 * 4096 + qc);
  p[1] = *(const float4*)(Xb + (long)r0 * 4096 + qc + 4);
  p[2] = *(const float4*)(Xb + (long)r1 * 4096 + qc);
  p[3] = *(const float4*)(Xb + (long)r1 * 4096 + qc + 4);
  stage8(p[0], p[1], lH[0] + r0 * LR + qc, lL[0] + r0 * LR + qc, xa0);
  stage8(p[2], p[3], lH[0] + r1 * LR + qc, lL[0] + r1 * LR + qc, xa1);
  __syncthreads();
  for (int kb = 0; kb < 8; ++kb) {
    const int cur = kb & 1, nxt = cur ^ 1;
    if (kb < 7) {  // issue next tile's loads; waitcnt lands after MFMA block
      const long kk = (kb + 1) * 32;
      p[0] = *(const float4*)(Xb + (long)r0 * 4096 + kk + qc);
      p[1] = *(const float4*)(Xb + (long)r0 * 4096 + kk + qc + 4);
      p[2] = *(const float4*)(Xb + (long)r1 * 4096 + kk + qc);
      p[3] = *(const float4*)(Xb + (long)r1 * 4096 + kk + qc + 4);
    }
    const u16* cH = lH[cur];
    const u16* cL = lL[cur];
#pragma unroll
    for (int j = 0; j < 4; ++j) {
      const short8 bh = *(const short8*)(cH + (wn + j * 16 + l16) * LR + quad * 8);
      const short8 bl = *(const short8*)(cL + (wn + j * 16 + l16) * LR + quad * 8);
#pragma unroll
      for (int i = 0; i < 8; ++i) {
        const short8 ah = *(const short8*)(cH + (wm + i * 16 + l16) * LR + quad * 8);
        const short8 al = *(const short8*)(cL + (wm + i * 16 + l16) * LR + quad * 8);
        acc[i][j] = __builtin_amdgcn_mfma_f32_16x16x32_bf16(ah, bh, acc[i][j], 0, 0, 0);
        acc[i][j] = __builtin_amdgcn_mfma_f32_16x16x32_bf16(ah, bl, acc[i][j], 0, 0, 0);
        acc[i][j] = __builtin_amdgcn_mfma_f32_16x16x32_bf16(al, bh, acc[i][j], 0, 0, 0);
      }
    }
    if (kb < 7) {
      stage8(p[0], p[1], lH[nxt] + r0 * LR + qc, lL[nxt] + r0 * LR + qc, xa0);
      stage8(p[2], p[3], lH[nxt] + r1 * LR + qc, lL[nxt] + r1 * LR + qc, xa1);
    }
    __syncthreads();
  }
  {
    float v = xa0;
    v += __shfl_xor(v, 1);
    v += __shfl_xor(v, 2);
    if ((t & 3) == 0) atomicAdd(&xsum[b * 256 + r0], v);
    v = xa1;
    v += __shfl_xor(v, 1);
    v += __shfl_xor(v, 2);
    if ((t & 3) == 0) atomicAdd(&xsum[b * 256 + r1], v);
  }
  float* G = Gf + (long)b * 65536;
#pragma unroll
  for (int i = 0; i < 8; ++i) {
    const int row0 = wm + i * 16 + quad * 4;
#pragma unroll
    for (int j = 0; j < 4; ++j) {
      const int col = wn + j * 16 + l16;
#pragma unroll
      for (int r = 0; r < 4; ++r)
        __hip_atomic_fetch_add(&G[(long)(row0 + r) * 256 + col], acc[i][j][r],
                               __ATOMIC_RELAXED, __HIP_MEMORY_SCOPE_AGENT);
    }
  }
}

// ---------------- Gf -> hi/lo bf16 ----------------
__global__ void split_g_kernel(const float* __restrict__ Gf, u16* __restrict__ Gh,
                               u16* __restrict__ Gl) {
  const long e = (long)blockIdx.x * 256 + threadIdx.x;  // 16*65536
  const float s = Gf[e];
  const u16 h = f2b(s);
  Gh[e] = h;
  Gl[e] = f2b(s - b2f(h));
}

// ------- small 256x256x256 TN GEMM: 64x64 tiles, 256-block grid ------------
// EPI: 0 = f32 store, 1 = bf16 hi/lo store, 2 = bf16 hi store
template <bool X3, int EPI>
__global__ __launch_bounds__(256) void gemm_small(
    const u16* __restrict__ Ah, const u16* __restrict__ Al,
    const u16* __restrict__ Bh, const u16* __restrict__ Bl,
    long aBatch, long bBatch, long oBatch,
    float* __restrict__ outF, u16* __restrict__ outH, u16* __restrict__ outL) {
  constexpr int LR = 40;
  __shared__ u16 smem[(X3 ? 4 : 2) * 64 * LR];
  u16* lAh = smem;
  u16* lBh = smem + 64 * LR;
  u16* lAl = X3 ? (smem + 2 * 64 * LR) : nullptr;
  u16* lBl = X3 ? (smem + 3 * 64 * LR) : nullptr;
  const int b = blockIdx.z;
  const int tm = blockIdx.x & 3, tn = blockIdx.x >> 2;  // 4x4 tiles of 64
  const u16* Ahb = Ah + (long)b * aBatch + (long)tm * 64 * 256;
  const u16* Bhb = Bh + (long)b * bBatch + (long)tn * 64 * 256;
  const u16* Alb = X3 ? (Al + (long)b * aBatch + (long)tm * 64 * 256) : nullptr;
  const u16* Blb = X3 ? (Bl + (long)b * bBatch + (long)tn * 64 * 256) : nullptr;
  const int t = threadIdx.x;
  const int lane = t & 63, wave = t >> 6;
  const int quad = lane >> 4, l16 = lane & 15;
  const int wm = (wave & 1) * 32, wn = (wave >> 1) * 32;
  const int r = t >> 2, qc = (t & 3) * 8;
  floatx4 acc[2][2] = {};
  for (int kk = 0; kk < 256; kk += 32) {
    __syncthreads();
    *(uint4*)(lAh + r * LR + qc) = *(const uint4*)(Ahb + (long)r * 256 + kk + qc);
    *(uint4*)(lBh + r * LR + qc) = *(const uint4*)(Bhb + (long)r * 256 + kk + qc);
    if (X3) {
      *(uint4*)(lAl + r * LR + qc) = *(const uint4*)(Alb + (long)r * 256 + kk + qc);
      *(uint4*)(lBl + r * LR + qc) = *(const uint4*)(Blb + (long)r * 256 + kk + qc);
    }
    __syncthreads();
    short8 afh[2], bfh[2], afl[2], bfl[2];
#pragma unroll
    for (int i = 0; i < 2; ++i) {
      afh[i] = *(const short8*)(lAh + (wm + i * 16 + l16) * LR + quad * 8);
      bfh[i] = *(const short8*)(lBh + (wn + i * 16 + l16) * LR + quad * 8);
      if (X3) {
        afl[i] = *(const short8*)(lAl + (wm + i * 16 + l16) * LR + quad * 8);
        bfl[i] = *(const short8*)(lBl + (wn + i * 16 + l16) * LR + quad * 8);
      }
    }
#pragma unroll
    for (int i = 0; i < 2; ++i)
#pragma unroll
      for (int j = 0; j < 2; ++j) {
        acc[i][j] = __builtin_amdgcn_mfma_f32_16x16x32_bf16(afh[i], bfh[j], acc[i][j], 0, 0, 0);
        if (X3) {
          acc[i][j] = __builtin_amdgcn_mfma_f32_16x16x32_bf16(afh[i], bfl[j], acc[i][j], 0, 0, 0);
          acc[i][j] = __builtin_amdgcn_mfma_f32_16x16x32_bf16(afl[i], bfh[j], acc[i][j], 0, 0, 0);
        }
      }
  }
  const long obase = (long)b * oBatch;
#pragma unroll
  for (int i = 0; i < 2; ++i) {
    const int mb = tm * 64 + wm + i * 16 + quad * 4;
#pragma unroll
    for (int j = 0; j < 2; ++j) {
      const int n = tn * 64 + wn + j * 16 + l16;
#pragma unroll
      for (int rr = 0; rr < 4; ++rr) {
        const float v = acc[i][j][rr];
        const long idx = obase + (long)(mb + rr) * 256 + n;
        if (EPI == 0) {
          outF[idx] = v;
        } else if (EPI == 1) {
          u16 h = f2b(v);
          outH[idx] = h;
          outL[idx] = f2b(v - b2f(h));
        } else {
          outH[idx] = f2b(v);
        }
      }
    }
  }
}

// ---------------- out = Mh * X^T + bb : 256x128 per block ------------------
// Full-M tiles so x is fetched exactly once. B staged with in-LDS transpose:
// e-row pairs packed as b32 writes, XOR-swizzled e-blocks.
__global__ __launch_bounds__(256, 2) void gemm_out(
    const u16* __restrict__ Mh, const float* __restrict__ x,
    const float* __restrict__ bb, float* __restrict__ out) {
  constexpr int LR = 40;
  __shared__ u16 lA[256 * LR], lB[128 * LR];
  const int b = blockIdx.z;
  const int tn = blockIdx.x;  // 0..31
  const u16* Ab = Mh + (long)b * 65536;
  const float* Xb = x + (long)b * 1048576 + tn * 128;
  const int t = threadIdx.x;
  const int lane = t & 63, wave = t >> 6;
  const int quad = lane >> 4, l16 = lane & 15;
  const int wm = wave * 64;
  const int erp = (t >> 4) * 2;   // e-row pair base 0..30
  const int n0 = (t & 15) * 8;    // n offset
  floatx4 acc[4][8] = {};
  for (int kk = 0; kk < 256; kk += 32) {
    __syncthreads();
#pragma unroll
    for (int h = 0; h < 4; ++h) {
      const int r = (t >> 2) + h * 64;
      *(uint4*)(lA + r * LR + (t & 3) * 8) =
          *(const uint4*)(Ab + (long)r * 256 + kk + (t & 3) * 8);
    }
    {
      const float4 a0 = *(const float4*)(Xb + (long)(kk + erp) * 4096 + n0);
      const float4 a1 = *(const float4*)(Xb + (long)(kk + erp) * 4096 + n0 + 4);
      const float4 c0 = *(const float4*)(Xb + (long)(kk + erp + 1) * 4096 + n0);
      const float4 c1 = *(const float4*)(Xb + (long)(kk + erp + 1) * 4096 + n0 + 4);
      const float fa[8] = {a0.x, a0.y, a0.z, a0.w, a1.x, a1.y, a1.z, a1.w};
      const float fc[8] = {c0.x, c0.y, c0.z, c0.w, c1.x, c1.y, c1.z, c1.w};
#pragma unroll
      for (int i = 0; i < 8; ++i) {
        const int nl = n0 + i;
        const int sb = (erp >> 3) ^ ((nl >> 4) & 3);  // swizzle e-block
        const unsigned int pk =
            (unsigned int)f2b(fa[i]) | ((unsigned int)f2b(fc[i]) << 16);
        *(unsigned int*)(lB + nl * LR + sb * 8 + (erp & 7)) = pk;
      }
    }
    __syncthreads();
    short8 af[4], bf[8];
#pragma unroll
    for (int j = 0; j < 8; ++j) {
      const int n = j * 16 + l16;
      const int rb = quad ^ ((n >> 4) & 3);
      bf[j] = *(const short8*)(lB + n * LR + rb * 8);
    }
#pragma unroll
    for (int i = 0; i < 4; ++i)
      af[i] = *(const short8*)(lA + (wm + i * 16 + l16) * LR + quad * 8);
#pragma unroll
    for (int i = 0; i < 4; ++i)
#pragma unroll
      for (int j = 0; j < 8; ++j)
        acc[i][j] = __builtin_amdgcn_mfma_f32_16x16x32_bf16(af[i], bf[j], acc[i][j], 0, 0, 0);
  }
  const long obase = (long)b * 1048576;
#pragma unroll
  for (int i = 0; i < 4; ++i) {
    const int mb = wm + i * 16 + quad * 4;
#pragma unroll
    for (int j = 0; j < 8; ++j) {
      const int n = tn * 128 + j * 16 + l16;
#pragma unroll
      for (int r = 0; r < 4; ++r)
        out[obase + (long)(mb + r) * 4096 + n] = acc[i][j][r] + bb[b * 256 + mb + r];
    }
  }
}

// ---------------- bias prep: s2[b][a]=w2[a,:]·xsum[b], s3 likewise --------
__global__ __launch_bounds__(512) void bias_prep_kernel(
    const float* __restrict__ w2, const float* __restrict__ w3,
    const float* __restrict__ xsum, float* __restrict__ S2, float* __restrict__ S3) {
  __shared__ float xs[256];
  const int b = blockIdx.x, t = threadIdx.x;
  if (t < 256) xs[t] = xsum[b * 256 + t];
  __syncthreads();
  const float* wm = (t < 256) ? w2 : w3;
  const int a = t & 255;
  float s = 0.f;
#pragma unroll 4
  for (int c = 0; c < 256; ++c) s += wm[a * 256 + c] * xs[c];
  if (t < 256) S2[b * 256 + a] = s;
  else         S3[b * 256 + a] = s;
}

// ---------------- softmax pass1: per-block (max, sumexp) ------------------
__global__ __launch_bounds__(256) void softmax_pass1(
    const float* __restrict__ Lt, const float* __restrict__ S2, const float* __restrict__ S3,
    const float* __restrict__ b2, const float* __restrict__ b3,
    float* __restrict__ bm, float* __restrict__ bs) {
  __shared__ float ls2[256], lb2[256];
  __shared__ float redm[4], reds[4];
  const int b = blockIdx.y, blk = blockIdx.x, t = threadIdx.x;
  ls2[t] = S2[b * 256 + t];
  lb2[t] = b2[t];
  __syncthreads();
  const int fw0 = blk * 2048 + t * 8;
  const int d = fw0 >> 8, a0 = fw0 & 255;
  const float c1 = b3[d];
  const float c0 = S3[b * 256 + d] + 4096.f * c1;
  const long base = (long)b * 65536 + fw0;
  float4 v0 = *(const float4*)(Lt + base);
  float4 v1 = *(const float4*)(Lt + base + 4);
  float v[8] = {v0.x, v0.y, v0.z, v0.w, v1.x, v1.y, v1.z, v1.w};
  float m = -3.4e38f;
#pragma unroll
  for (int i = 0; i < 8; ++i) {
    v[i] += lb2[a0 + i] * c0 + c1 * ls2[a0 + i];
    m = fmaxf(m, v[i]);
  }
  for (int o = 32; o; o >>= 1) m = fmaxf(m, __shfl_xor(m, o));
  const int wid = t >> 6, lane = t & 63;
  if (lane == 0) redm[wid] = m;
  __syncthreads();
  const float bmax = fmaxf(fmaxf(redm[0], redm[1]), fmaxf(redm[2], redm[3]));
  float s = 0.f;
#pragma unroll
  for (int i = 0; i < 8; ++i) s += __expf(v[i] - bmax);
  for (int o = 32; o; o >>= 1) s += __shfl_xor(s, o);
  if (lane == 0) reds[wid] = s;
  __syncthreads();
  if (t == 0) {
    bm[b * 32 + blk] = bmax;
    bs[b * 32 + blk] = reds[0] + reds[1] + reds[2] + reds[3];
  }
}

// -- softmax pass3: inline combine + write WT bf16 + fused bb[d]=WT·b1 ------
__global__ __launch_bounds__(256) void softmax_pass3(
    const float* __restrict__ Lt, const float* __restrict__ S2, const float* __restrict__ S3,
    const float* __restrict__ b2, const float* __restrict__ b3,
    const float* __restrict__ bm, const float* __restrict__ bs,
    const float* __restrict__ b1, u16* __restrict__ WTh, float* __restrict__ bb) {
  __shared__ float ls2[256], lb2[256], lb1[256];
  __shared__ float sM, sInv;
  const int b = blockIdx.y, blk = blockIdx.x, t = threadIdx.x;
  if (t < 64) {  // combine 32 block pairs (wave 0 only)
    const float m = (t < 32) ? bm[b * 32 + t] : -3.4e38f;
    float s = (t < 32) ? bs[b * 32 + t] : 0.f;
    float M = m;
    for (int o = 32; o; o >>= 1) M = fmaxf(M, __shfl_xor(M, o));
    s *= __expf(m - M);
    for (int o = 32; o; o >>= 1) s += __shfl_xor(s, o);
    if (t == 0) { sM = M; sInv = 1.0f / s; }
  }
  ls2[t] = S2[b * 256 + t];
  lb2[t] = b2[t];
  lb1[t] = b1[t];
  __syncthreads();
  const float M = sM, inv = sInv;
  const int fw0 = blk * 2048 + t * 8;
  const int d = fw0 >> 8, a0 = fw0 & 255;
  const float c1 = b3[d];
  const float c0 = S3[b * 256 + d] + 4096.f * c1;
  const long base = (long)b * 65536 + fw0;
  float4 v0 = *(const float4*)(Lt + base);
  float4 v1 = *(const float4*)(Lt + base + 4);
  float v[8] = {v0.x, v0.y, v0.z, v0.w, v1.x, v1.y, v1.z, v1.w};
  union { u16 h[8]; uint4 q; } o;
  float bsum = 0.f;
#pragma unroll
  for (int i = 0; i < 8; ++i) {
    const float vv = v[i] + lb2[a0 + i] * c0 + c1 * ls2[a0 + i];
    const float w = __expf(vv - M) * inv;
    o.h[i] = f2b(w);
    bsum += w * lb1[a0 + i];
  }
  *(uint4*)(WTh + base) = o.q;
  // row d spans 32 consecutive threads (t*8 covers 256 a per 32 threads)
  for (int off = 16; off; off >>= 1) bsum += __shfl_xor(bsum, off);
  if ((t & 31) == 0) bb[b * 256 + d] = bsum;
}

extern "C" void kernel_launch(void* const* d_in, const int* in_sizes, int n_in,
                              void* d_out, int out_size, void* d_ws, size_t ws_size,
                              hipStream_t stream) {
  const float* x  = (const float*)d_in[0];
  const float* w1 = (const float*)d_in[1];
  const float* b1 = (const float*)d_in[2];
  const float* w2 = (const float*)d_in[3];
  const float* b2 = (const float*)d_in[4];
  const float* w3 = (const float*)d_in[5];
  const float* b3 = (const float*)d_in[6];
  float* out = (float*)d_out;

  char* ws = (char*)d_ws;
  size_t off = 0;
  auto alloc = [&](size_t bytes) {
    void* p = ws + off;
    off += (bytes + 255) & ~(size_t)255;
    return p;
  };
  // Gf + xsum contiguous -> single memset
  float* Gf   = (float*)alloc(16ull * 65536 * 4);      // 4 MiB accumulators
  float* xsum = (float*)alloc(16 * 256 * 4);
  u16* Gh   = (u16*)alloc(16ull * 65536 * 2);
  u16* Gl   = (u16*)alloc(16ull * 65536 * 2);
  u16* T3h  = (u16*)alloc(16ull * 65536 * 2);
  u16* T3l  = (u16*)alloc(16ull * 65536 * 2);
  float* Lb = (float*)alloc(16ull * 65536 * 4);        // Lt[d][a]
  u16* WTh  = (u16*)alloc(16ull * 65536 * 2);
  u16* Mh   = (u16*)alloc(16ull * 65536 * 2);
  u16* W1Th = (u16*)alloc(65536 * 2);
  u16* W2h  = (u16*)alloc(65536 * 2);
  u16* W2l  = (u16*)alloc(65536 * 2);
  u16* W3h  = (u16*)alloc(65536 * 2);
  u16* W3l  = (u16*)alloc(65536 * 2);
  float* S2   = (float*)alloc(16 * 256 * 4);
  float* S3   = (float*)alloc(16 * 256 * 4);
  float* bmx  = (float*)alloc(16 * 32 * 4);
  float* bsx  = (float*)alloc(16 * 32 * 4);
  float* bb   = (float*)alloc(16 * 256 * 4);

  hipMemsetAsync(Gf, 0, 16ull * 65536 * 4 + 16 * 256 * 4, stream);
  prep_w_kernel<<<576, 256, 0, stream>>>(w1, w2, w3, W1Th, W2h, W2l, W3h, W3l);

  // Gram: 16 batches x 16 n-splits, full 256x256 each, atomic accumulate.
  gram_kernel<<<256, 512, 0, stream>>>(x, Gf, xsum);
  split_g_kernel<<<4096, 256, 0, stream>>>(Gf, Gh, Gl);

  // T3 = W3 * G (G symmetric -> TN ok). 64x64 tiles, 256 blocks.
  gemm_small<true, 1><<<dim3(16, 1, 16), 256, 0, stream>>>(
      W3h, W3l, Gh, Gl, 0, 65536, 65536, nullptr, T3h, T3l);
  // Lt = T3 * W2^T  ->  Lt[d][a] = logits[a][d].
  gemm_small<true, 0><<<dim3(16, 1, 16), 256, 0, stream>>>(
      T3h, T3l, W2h, W2l, 65536, 0, 65536, Lb, nullptr, nullptr);

  // softmax: bias prep + pass1 + fused combine/write/bb pass3
  bias_prep_kernel<<<16, 512, 0, stream>>>(w2, w3, xsum, S2, S3);
  softmax_pass1<<<dim3(32, 16), 256, 0, stream>>>(Lb, S2, S3, b2, b3, bmx, bsx);
  softmax_pass3<<<dim3(32, 16), 256, 0, stream>>>(Lb, S2, S3, b2, b3, bmx, bsx,
                                                  b1, WTh, bb);

  // out-chain: Mh = WT*W1T (bf16), out = Mh*X^T + bb
  gemm_small<false, 2><<<dim3(16, 1, 16), 256, 0, stream>>>(
      WTh, nullptr, W1Th, nullptr, 65536, 0, 65536, nullptr, Mh, nullptr);
  gemm_out<<<dim3(32, 1, 16), 256, 0, stream>>>(Mh, x, bb, out);
}

// Round 9
// 221.753 us; speedup vs baseline: 1.1429x; 1.1429x over previous
//
#include <hip/hip_runtime.h>

// GlobalChannelAttention: B=16, C=256, H*W=4096
//
// Pipeline (TN-form GEMMs: C[M,N] = sum_k A[m][k]*B[n][k], K contiguous):
//   1. prep_w: w1 -> W1Th (bf16 transposed), w2/w3 -> hi/lo bf16
//   2. gram: G[b] = X X^T from raw x f32 (hi/lo split into SEPARATE LDS
//      slabs, 3 MFMAs: hh + hl + lh -- cross terms REQUIRED; R8's k-interleave
//      dropped them and failed 0.14 > 0.089). One 512-thr block per
//      (batch, n-split/16), full 256x256, double-buffered, f32 partials.
//   3. reduce_g: sum 16 partials -> Gh/Gl bf16. T3 = W3*G (G symmetric),
//      Lt = T3*W2^T == logits TRANSPOSED (Lt[d][a]); 64x64 tiles, 256 blocks.
//   4. global softmax: pass1 block partials; pass3 combine + write WT bf16
//      + fused bb[d] = sum_c WT[d][c]*b1[c].
//   5. Mh = WT*W1T (bf16); out = Mh*X^T + bb, B straight from x f32 with
//      in-LDS transpose (pair-packed b32, XOR swizzle), 256x128 full-M tiles.
//
// Precision: logit chain bf16 hi/lo x3 (err ~2^-17 rel); out chain plain bf16.
// R7 post-mortem: atomic-f32 Gram epilogue regressed 41->78us (16-way
// same-address L2 contention). R8 post-mortem: k-interleaved hi/lo loses the
// hi*lo cross terms (slot k of A only meets slot k of B) -> accuracy fail.

typedef unsigned short u16;
typedef __attribute__((ext_vector_type(8))) short short8;
typedef __attribute__((ext_vector_type(4))) float floatx4;

__device__ __forceinline__ u16 f2b(float f) {
  union { float f; unsigned int u; } v; v.f = f;
  unsigned int u = v.u;
  return (u16)((u + 0x7fffu + ((u >> 16) & 1u)) >> 16);  // RNE
}
__device__ __forceinline__ float b2f(u16 h) {
  union { unsigned int u; float f; } v; v.u = ((unsigned int)h) << 16;
  return v.f;
}

// ---------------- merged W prep: transpose w1 + split w2/w3 ----------------
__global__ __launch_bounds__(256) void prep_w_kernel(
    const float* __restrict__ w1, const float* __restrict__ w2, const float* __restrict__ w3,
    u16* __restrict__ W1Th, u16* __restrict__ W2h, u16* __restrict__ W2l,
    u16* __restrict__ W3h, u16* __restrict__ W3l) {
  const int blk = blockIdx.x, t = threadIdx.x;
  if (blk < 64) {  // W1Th[e][c] = w1[c][e]
    __shared__ float tile[32][33];
    const int e0 = (blk & 7) * 32, c0 = (blk >> 3) * 32;
    const int tx = t & 31, ty = t >> 5;
#pragma unroll
    for (int i = 0; i < 4; ++i)
      tile[ty + i * 8][tx] = w1[(c0 + ty + i * 8) * 256 + e0 + tx];
    __syncthreads();
#pragma unroll
    for (int i = 0; i < 4; ++i)
      W1Th[(e0 + ty + i * 8) * 256 + c0 + tx] = f2b(tile[tx][ty + i * 8]);
  } else {
    const int i = (blk - 64) * 256 + t;  // 0..131071
    const int e = i & 0xffff;
    const float f = (i >> 16) ? w3[e] : w2[e];
    u16 h = f2b(f);
    if (i >> 16) { W3h[e] = h; W3l[e] = f2b(f - b2f(h)); }
    else         { W2h[e] = h; W2l[e] = f2b(f - b2f(h)); }
  }
}

// ---- stage 8 f32 -> hi/lo bf16 LDS (one uint4 each) + running sum --------
__device__ __forceinline__ void stage8(const float4 a, const float4 b,
                                       u16* dH, u16* dL, float& xa) {
  const float f[8] = {a.x, a.y, a.z, a.w, b.x, b.y, b.z, b.w};
  union { u16 h8[8]; uint4 q; } uh, ul;
#pragma unroll
  for (int i = 0; i < 8; ++i) {
    const u16 hi = f2b(f[i]);
    uh.h8[i] = hi;
    ul.h8[i] = f2b(f[i] - b2f(hi));
    xa += f[i];
  }
  *(uint4*)dH = uh.q;
  *(uint4*)dL = ul.q;
}

// ---------------- Gram from raw x: full 256x256 per (batch, split) ---------
// 512 threads / 8 waves; wave (wm in {0,128}, wn in {0,64,128,192}) does 128x64.
// Separate hi/lo slabs (3 MFMAs incl cross terms), double-buffered LDS.
__global__ __launch_bounds__(512, 2) void gram_kernel(
    const float* __restrict__ x, float* __restrict__ Gp, float* __restrict__ xsum) {
  constexpr int LR = 40;  // +8 pad: 2-way bank aliasing only (free per m136)
  __shared__ u16 lH[2][256 * LR], lL[2][256 * LR];  // 80 KB total
  const int b = blockIdx.x >> 4, s = blockIdx.x & 15;
  const float* Xb = x + (long)b * 1048576 + s * 256;
  const int t = threadIdx.x;
  const int lane = t & 63, wave = t >> 6;
  const int quad = lane >> 4, l16 = lane & 15;
  const int wm = (wave & 1) * 128, wn = (wave >> 1) * 64;
  const int r0 = t >> 2, qc = (t & 3) * 8;
  const int r1 = r0 + 128;
  floatx4 acc[8][4] = {};
  float xa0 = 0.f, xa1 = 0.f;
  float4 p[4];
  p[0] = *(const float4*)(Xb + (long)r0 * 4096 + qc);
  p[1] = *(const float4*)(Xb + (long)r0 * 4096 + qc + 4);
  p[2] = *(const float4*)(Xb + (long)r1 * 4096 + qc);
  p[3] = *(const float4*)(Xb + (long)r1 * 4096 + qc + 4);
  stage8(p[0], p[1], lH[0] + r0 * LR + qc, lL[0] + r0 * LR + qc, xa0);
  stage8(p[2], p[3], lH[0] + r1 * LR + qc, lL[0] + r1 * LR + qc, xa1);
  __syncthreads();
  for (int kb = 0; kb < 8; ++kb) {
    const int cur = kb & 1, nxt = cur ^ 1;
    if (kb < 7) {  // issue next tile's loads; waitcnt lands after MFMA block
      const long kk = (kb + 1) * 32;
      p[0] = *(const float4*)(Xb + (long)r0 * 4096 + kk + qc);
      p[1] = *(const float4*)(Xb + (long)r0 * 4096 + kk + qc + 4);
      p[2] = *(const float4*)(Xb + (long)r1 * 4096 + kk + qc);
      p[3] = *(const float4*)(Xb + (long)r1 * 4096 + kk + qc + 4);
    }
    const u16* cH = lH[cur];
    const u16* cL = lL[cur];
#pragma unroll
    for (int j = 0; j < 4; ++j) {
      const short8 bh = *(const short8*)(cH + (wn + j * 16 + l16) * LR + quad * 8);
      const short8 bl = *(const short8*)(cL + (wn + j * 16 + l16) * LR + quad * 8);
#pragma unroll
      for (int i = 0; i < 8; ++i) {
        const short8 ah = *(const short8*)(cH + (wm + i * 16 + l16) * LR + quad * 8);
        const short8 al = *(const short8*)(cL + (wm + i * 16 + l16) * LR + quad * 8);
        acc[i][j] = __builtin_amdgcn_mfma_f32_16x16x32_bf16(ah, bh, acc[i][j], 0, 0, 0);
        acc[i][j] = __builtin_amdgcn_mfma_f32_16x16x32_bf16(ah, bl, acc[i][j], 0, 0, 0);
        acc[i][j] = __builtin_amdgcn_mfma_f32_16x16x32_bf16(al, bh, acc[i][j], 0, 0, 0);
      }
    }
    if (kb < 7) {
      stage8(p[0], p[1], lH[nxt] + r0 * LR + qc, lL[nxt] + r0 * LR + qc, xa0);
      stage8(p[2], p[3], lH[nxt] + r1 * LR + qc, lL[nxt] + r1 * LR + qc, xa1);
    }
    __syncthreads();
  }
  {
    float v = xa0;
    v += __shfl_xor(v, 1);
    v += __shfl_xor(v, 2);
    if ((t & 3) == 0) atomicAdd(&xsum[b * 256 + r0], v);
    v = xa1;
    v += __shfl_xor(v, 1);
    v += __shfl_xor(v, 2);
    if ((t & 3) == 0) atomicAdd(&xsum[b * 256 + r1], v);
  }
  float* G = Gp + ((long)b * 16 + s) * 65536;
#pragma unroll
  for (int i = 0; i < 8; ++i) {
    const int row0 = wm + i * 16 + quad * 4;
#pragma unroll
    for (int j = 0; j < 4; ++j) {
      const int col = wn + j * 16 + l16;
#pragma unroll
      for (int r = 0; r < 4; ++r)
        G[(long)(row0 + r) * 256 + col] = acc[i][j][r];
    }
  }
}

// ---------------- Gram split-K reduction + hi/lo split ----------------
__global__ void reduce_g_kernel(const float* __restrict__ Gp, u16* __restrict__ Gh,
                                u16* __restrict__ Gl) {
  const long e = (long)blockIdx.x * 256 + threadIdx.x;  // over 16*65536
  const long base = ((e >> 16) << 20) + (e & 65535);    // b*16*65536 + idx
  float s = 0.f;
#pragma unroll
  for (int i = 0; i < 16; ++i) s += Gp[base + (long)i * 65536];
  u16 h = f2b(s);
  Gh[e] = h;
  Gl[e] = f2b(s - b2f(h));
}

// ------- small 256x256x256 TN GEMM: 64x64 tiles, 256-block grid ------------
// EPI: 0 = f32 store, 1 = bf16 hi/lo store, 2 = bf16 hi store
template <bool X3, int EPI>
__global__ __launch_bounds__(256) void gemm_small(
    const u16* __restrict__ Ah, const u16* __restrict__ Al,
    const u16* __restrict__ Bh, const u16* __restrict__ Bl,
    long aBatch, long bBatch, long oBatch,
    float* __restrict__ outF, u16* __restrict__ outH, u16* __restrict__ outL) {
  constexpr int LR = 40;
  __shared__ u16 smem[(X3 ? 4 : 2) * 64 * LR];
  u16* lAh = smem;
  u16* lBh = smem + 64 * LR;
  u16* lAl = X3 ? (smem + 2 * 64 * LR) : nullptr;
  u16* lBl = X3 ? (smem + 3 * 64 * LR) : nullptr;
  const int b = blockIdx.z;
  const int tm = blockIdx.x & 3, tn = blockIdx.x >> 2;  // 4x4 tiles of 64
  const u16* Ahb = Ah + (long)b * aBatch + (long)tm * 64 * 256;
  const u16* Bhb = Bh + (long)b * bBatch + (long)tn * 64 * 256;
  const u16* Alb = X3 ? (Al + (long)b * aBatch + (long)tm * 64 * 256) : nullptr;
  const u16* Blb = X3 ? (Bl + (long)b * bBatch + (long)tn * 64 * 256) : nullptr;
  const int t = threadIdx.x;
  const int lane = t & 63, wave = t >> 6;
  const int quad = lane >> 4, l16 = lane & 15;
  const int wm = (wave & 1) * 32, wn = (wave >> 1) * 32;
  const int r = t >> 2, qc = (t & 3) * 8;
  floatx4 acc[2][2] = {};
  for (int kk = 0; kk < 256; kk += 32) {
    __syncthreads();
    *(uint4*)(lAh + r * LR + qc) = *(const uint4*)(Ahb + (long)r * 256 + kk + qc);
    *(uint4*)(lBh + r * LR + qc) = *(const uint4*)(Bhb + (long)r * 256 + kk + qc);
    if (X3) {
      *(uint4*)(lAl + r * LR + qc) = *(const uint4*)(Alb + (long)r * 256 + kk + qc);
      *(uint4*)(lBl + r * LR + qc) = *(const uint4*)(Blb + (long)r * 256 + kk + qc);
    }
    __syncthreads();
    short8 afh[2], bfh[2], afl[2], bfl[2];
#pragma unroll
    for (int i = 0; i < 2; ++i) {
      afh[i] = *(const short8*)(lAh + (wm + i * 16 + l16) * LR + quad * 8);
      bfh[i] = *(const short8*)(lBh + (wn + i * 16 + l16) * LR + quad * 8);
      if (X3) {
        afl[i] = *(const short8*)(lAl + (wm + i * 16 + l16) * LR + quad * 8);
        bfl[i] = *(const short8*)(lBl + (wn + i * 16 + l16) * LR + quad * 8);
      }
    }
#pragma unroll
    for (int i = 0; i < 2; ++i)
#pragma unroll
      for (int j = 0; j < 2; ++j) {
        acc[i][j] = __builtin_amdgcn_mfma_f32_16x16x32_bf16(afh[i], bfh[j], acc[i][j], 0, 0, 0);
        if (X3) {
          acc[i][j] = __builtin_amdgcn_mfma_f32_16x16x32_bf16(afh[i], bfl[j], acc[i][j], 0, 0, 0);
          acc[i][j] = __builtin_amdgcn_mfma_f32_16x16x32_bf16(afl[i], bfh[j], acc[i][j], 0, 0, 0);
        }
      }
  }
  const long obase = (long)b * oBatch;
#pragma unroll
  for (int i = 0; i < 2; ++i) {
    const int mb = tm * 64 + wm + i * 16 + quad * 4;
#pragma unroll
    for (int j = 0; j < 2; ++j) {
      const int n = tn * 64 + wn + j * 16 + l16;
#pragma unroll
      for (int rr = 0; rr < 4; ++rr) {
        const float v = acc[i][j][rr];
        const long idx = obase + (long)(mb + rr) * 256 + n;
        if (EPI == 0) {
          outF[idx] = v;
        } else if (EPI == 1) {
          u16 h = f2b(v);
          outH[idx] = h;
          outL[idx] = f2b(v - b2f(h));
        } else {
          outH[idx] = f2b(v);
        }
      }
    }
  }
}

// ---------------- out = Mh * X^T + bb : 256x128 per block ------------------
// Full-M tiles so x is fetched exactly once. B staged with in-LDS transpose:
// e-row pairs packed as b32 writes, XOR-swizzled e-blocks.
__global__ __launch_bounds__(256, 2) void gemm_out(
    const u16* __restrict__ Mh, const float* __restrict__ x,
    const float* __restrict__ bb, float* __restrict__ out) {
  constexpr int LR = 40;
  __shared__ u16 lA[256 * LR], lB[128 * LR];
  const int b = blockIdx.z;
  const int tn = blockIdx.x;  // 0..31
  const u16* Ab = Mh + (long)b * 65536;
  const float* Xb = x + (long)b * 1048576 + tn * 128;
  const int t = threadIdx.x;
  const int lane = t & 63, wave = t >> 6;
  const int quad = lane >> 4, l16 = lane & 15;
  const int wm = wave * 64;
  const int erp = (t >> 4) * 2;   // e-row pair base 0..30
  const int n0 = (t & 15) * 8;    // n offset
  floatx4 acc[4][8] = {};
  for (int kk = 0; kk < 256; kk += 32) {
    __syncthreads();
#pragma unroll
    for (int h = 0; h < 4; ++h) {
      const int r = (t >> 2) + h * 64;
      *(uint4*)(lA + r * LR + (t & 3) * 8) =
          *(const uint4*)(Ab + (long)r * 256 + kk + (t & 3) * 8);
    }
    {
      const float4 a0 = *(const float4*)(Xb + (long)(kk + erp) * 4096 + n0);
      const float4 a1 = *(const float4*)(Xb + (long)(kk + erp) * 4096 + n0 + 4);
      const float4 c0 = *(const float4*)(Xb + (long)(kk + erp + 1) * 4096 + n0);
      const float4 c1 = *(const float4*)(Xb + (long)(kk + erp + 1) * 4096 + n0 + 4);
      const float fa[8] = {a0.x, a0.y, a0.z, a0.w, a1.x, a1.y, a1.z, a1.w};
      const float fc[8] = {c0.x, c0.y, c0.z, c0.w, c1.x, c1.y, c1.z, c1.w};
#pragma unroll
      for (int i = 0; i < 8; ++i) {
        const int nl = n0 + i;
        const int sb = (erp >> 3) ^ ((nl >> 4) & 3);  // swizzle e-block
        const unsigned int pk =
            (unsigned int)f2b(fa[i]) | ((unsigned int)f2b(fc[i]) << 16);
        *(unsigned int*)(lB + nl * LR + sb * 8 + (erp & 7)) = pk;
      }
    }
    __syncthreads();
    short8 af[4], bf[8];
#pragma unroll
    for (int j = 0; j < 8; ++j) {
      const int n = j * 16 + l16;
      const int rb = quad ^ ((n >> 4) & 3);
      bf[j] = *(const short8*)(lB + n * LR + rb * 8);
    }
#pragma unroll
    for (int i = 0; i < 4; ++i)
      af[i] = *(const short8*)(lA + (wm + i * 16 + l16) * LR + quad * 8);
#pragma unroll
    for (int i = 0; i < 4; ++i)
#pragma unroll
      for (int j = 0; j < 8; ++j)
        acc[i][j] = __builtin_amdgcn_mfma_f32_16x16x32_bf16(af[i], bf[j], acc[i][j], 0, 0, 0);
  }
  const long obase = (long)b * 1048576;
#pragma unroll
  for (int i = 0; i < 4; ++i) {
    const int mb = wm + i * 16 + quad * 4;
#pragma unroll
    for (int j = 0; j < 8; ++j) {
      const int n = tn * 128 + j * 16 + l16;
#pragma unroll
      for (int r = 0; r < 4; ++r)
        out[obase + (long)(mb + r) * 4096 + n] = acc[i][j][r] + bb[b * 256 + mb + r];
    }
  }
}

// ---------------- bias prep: s2[b][a]=w2[a,:]·xsum[b], s3 likewise --------
__global__ __launch_bounds__(512) void bias_prep_kernel(
    const float* __restrict__ w2, const float* __restrict__ w3,
    const float* __restrict__ xsum, float* __restrict__ S2, float* __restrict__ S3) {
  __shared__ float xs[256];
  const int b = blockIdx.x, t = threadIdx.x;
  if (t < 256) xs[t] = xsum[b * 256 + t];
  __syncthreads();
  const float* wm = (t < 256) ? w2 : w3;
  const int a = t & 255;
  float s = 0.f;
#pragma unroll 4
  for (int c = 0; c < 256; ++c) s += wm[a * 256 + c] * xs[c];
  if (t < 256) S2[b * 256 + a] = s;
  else         S3[b * 256 + a] = s;
}

// ---------------- softmax pass1: per-block (max, sumexp) ------------------
__global__ __launch_bounds__(256) void softmax_pass1(
    const float* __restrict__ Lt, const float* __restrict__ S2, const float* __restrict__ S3,
    const float* __restrict__ b2, const float* __restrict__ b3,
    float* __restrict__ bm, float* __restrict__ bs) {
  __shared__ float ls2[256], lb2[256];
  __shared__ float redm[4], reds[4];
  const int b = blockIdx.y, blk = blockIdx.x, t = threadIdx.x;
  ls2[t] = S2[b * 256 + t];
  lb2[t] = b2[t];
  __syncthreads();
  const int fw0 = blk * 2048 + t * 8;
  const int d = fw0 >> 8, a0 = fw0 & 255;
  const float c1 = b3[d];
  const float c0 = S3[b * 256 + d] + 4096.f * c1;
  const long base = (long)b * 65536 + fw0;
  float4 v0 = *(const float4*)(Lt + base);
  float4 v1 = *(const float4*)(Lt + base + 4);
  float v[8] = {v0.x, v0.y, v0.z, v0.w, v1.x, v1.y, v1.z, v1.w};
  float m = -3.4e38f;
#pragma unroll
  for (int i = 0; i < 8; ++i) {
    v[i] += lb2[a0 + i] * c0 + c1 * ls2[a0 + i];
    m = fmaxf(m, v[i]);
  }
  for (int o = 32; o; o >>= 1) m = fmaxf(m, __shfl_xor(m, o));
  const int wid = t >> 6, lane = t & 63;
  if (lane == 0) redm[wid] = m;
  __syncthreads();
  const float bmax = fmaxf(fmaxf(redm[0], redm[1]), fmaxf(redm[2], redm[3]));
  float s = 0.f;
#pragma unroll
  for (int i = 0; i < 8; ++i) s += __expf(v[i] - bmax);
  for (int o = 32; o; o >>= 1) s += __shfl_xor(s, o);
  if (lane == 0) reds[wid] = s;
  __syncthreads();
  if (t == 0) {
    bm[b * 32 + blk] = bmax;
    bs[b * 32 + blk] = reds[0] + reds[1] + reds[2] + reds[3];
  }
}

// -- softmax pass3: inline combine + write WT bf16 + fused bb[d]=WT·b1 ------
__global__ __launch_bounds__(256) void softmax_pass3(
    const float* __restrict__ Lt, const float* __restrict__ S2, const float* __restrict__ S3,
    const float* __restrict__ b2, const float* __restrict__ b3,
    const float* __restrict__ bm, const float* __restrict__ bs,
    const float* __restrict__ b1, u16* __restrict__ WTh, float* __restrict__ bb) {
  __shared__ float ls2[256], lb2[256], lb1[256];
  __shared__ float sM, sInv;
  const int b = blockIdx.y, blk = blockIdx.x, t = threadIdx.x;
  if (t < 64) {  // combine 32 block pairs (wave 0 only)
    const float m = (t < 32) ? bm[b * 32 + t] : -3.4e38f;
    float s = (t < 32) ? bs[b * 32 + t] : 0.f;
    float M = m;
    for (int o = 32; o; o >>= 1) M = fmaxf(M, __shfl_xor(M, o));
    s *= __expf(m - M);
    for (int o = 32; o; o >>= 1) s += __shfl_xor(s, o);
    if (t == 0) { sM = M; sInv = 1.0f / s; }
  }
  ls2[t] = S2[b * 256 + t];
  lb2[t] = b2[t];
  lb1[t] = b1[t];
  __syncthreads();
  const float M = sM, inv = sInv;
  const int fw0 = blk * 2048 + t * 8;
  const int d = fw0 >> 8, a0 = fw0 & 255;
  const float c1 = b3[d];
  const float c0 = S3[b * 256 + d] + 4096.f * c1;
  const long base = (long)b * 65536 + fw0;
  float4 v0 = *(const float4*)(Lt + base);
  float4 v1 = *(const float4*)(Lt + base + 4);
  float v[8] = {v0.x, v0.y, v0.z, v0.w, v1.x, v1.y, v1.z, v1.w};
  union { u16 h[8]; uint4 q; } o;
  float bsum = 0.f;
#pragma unroll
  for (int i = 0; i < 8; ++i) {
    const float vv = v[i] + lb2[a0 + i] * c0 + c1 * ls2[a0 + i];
    const float w = __expf(vv - M) * inv;
    o.h[i] = f2b(w);
    bsum += w * lb1[a0 + i];
  }
  *(uint4*)(WTh + base) = o.q;
  // row d spans 32 consecutive threads
  for (int off = 16; off; off >>= 1) bsum += __shfl_xor(bsum, off);
  if ((t & 31) == 0) bb[b * 256 + d] = bsum;
}

extern "C" void kernel_launch(void* const* d_in, const int* in_sizes, int n_in,
                              void* d_out, int out_size, void* d_ws, size_t ws_size,
                              hipStream_t stream) {
  const float* x  = (const float*)d_in[0];
  const float* w1 = (const float*)d_in[1];
  const float* b1 = (const float*)d_in[2];
  const float* w2 = (const float*)d_in[3];
  const float* b2 = (const float*)d_in[4];
  const float* w3 = (const float*)d_in[5];
  const float* b3 = (const float*)d_in[6];
  float* out = (float*)d_out;

  char* ws = (char*)d_ws;
  size_t off = 0;
  auto alloc = [&](size_t bytes) {
    void* p = ws + off;
    off += (bytes + 255) & ~(size_t)255;
    return p;
  };
  float* Gp = (float*)alloc(16ull * 16 * 65536 * 4);   // 64 MiB split-K partials
  float* xsum = (float*)alloc(16 * 256 * 4);
  u16* Gh   = (u16*)alloc(16ull * 65536 * 2);
  u16* Gl   = (u16*)alloc(16ull * 65536 * 2);
  u16* T3h  = (u16*)alloc(16ull * 65536 * 2);
  u16* T3l  = (u16*)alloc(16ull * 65536 * 2);
  float* Lb = (float*)alloc(16ull * 65536 * 4);        // Lt[d][a]
  u16* WTh  = (u16*)alloc(16ull * 65536 * 2);
  u16* Mh   = (u16*)alloc(16ull * 65536 * 2);
  u16* W1Th = (u16*)alloc(65536 * 2);
  u16* W2h  = (u16*)alloc(65536 * 2);
  u16* W2l  = (u16*)alloc(65536 * 2);
  u16* W3h  = (u16*)alloc(65536 * 2);
  u16* W3l  = (u16*)alloc(65536 * 2);
  float* S2   = (float*)alloc(16 * 256 * 4);
  float* S3   = (float*)alloc(16 * 256 * 4);
  float* bmx  = (float*)alloc(16 * 32 * 4);
  float* bsx  = (float*)alloc(16 * 32 * 4);
  float* bb   = (float*)alloc(16 * 256 * 4);

  hipMemsetAsync(xsum, 0, 16 * 256 * 4, stream);
  prep_w_kernel<<<576, 256, 0, stream>>>(w1, w2, w3, W1Th, W2h, W2l, W3h, W3l);

  // Gram partials: 16 batches x 16 n-splits, full 256x256 each.
  gram_kernel<<<256, 512, 0, stream>>>(x, Gp, xsum);
  reduce_g_kernel<<<4096, 256, 0, stream>>>(Gp, Gh, Gl);

  // T3 = W3 * G (G symmetric -> TN ok). 64x64 tiles, 256 blocks.
  gemm_small<true, 1><<<dim3(16, 1, 16), 256, 0, stream>>>(
      W3h, W3l, Gh, Gl, 0, 65536, 65536, nullptr, T3h, T3l);
  // Lt = T3 * W2^T  ->  Lt[d][a] = logits[a][d].
  gemm_small<true, 0><<<dim3(16, 1, 16), 256, 0, stream>>>(
      T3h, T3l, W2h, W2l, 65536, 0, 65536, Lb, nullptr, nullptr);

  // softmax: bias prep + pass1 + fused combine/write/bb pass3
  bias_prep_kernel<<<16, 512, 0, stream>>>(w2, w3, xsum, S2, S3);
  softmax_pass1<<<dim3(32, 16), 256, 0, stream>>>(Lb, S2, S3, b2, b3, bmx, bsx);
  softmax_pass3<<<dim3(32, 16), 256, 0, stream>>>(Lb, S2, S3, b2, b3, bmx, bsx,
                                                  b1, WTh, bb);

  // out-chain: Mh = WT*W1T (bf16), out = Mh*X^T + bb
  gemm_small<false, 2><<<dim3(16, 1, 16), 256, 0, stream>>>(
      WTh, nullptr, W1Th, nullptr, 65536, 0, 65536, nullptr, Mh, nullptr);
  gemm_out<<<dim3(32, 1, 16), 256, 0, stream>>>(Mh, x, bb, out);
}

// Round 10
// 219.960 us; speedup vs baseline: 1.1522x; 1.0081x over previous
//
#include <hip/hip_runtime.h>

// GlobalChannelAttention: B=16, C=256, H*W=4096
//
// Pipeline (TN-form GEMMs: C[M,N] = sum_k A[m][k]*B[n][k], K contiguous):
//   1. prep_w: w1 -> W1Th (bf16 transposed), w2/w3 -> hi/lo bf16, zero xsum
//   2. gram: G[b] = X X^T from raw x f32 (hi/lo in SEPARATE LDS slabs, 3
//      MFMAs hh+hl+lh). HALF-M blocks: grid 16b x 8splits x 2mhalf, each
//      512-thr block computes 128x256 over k-chunk 512, wave tiles 64x64 ->
//      acc 4x4 (64 VGPR) so A/B fragments stay hoisted in registers
//      (R9 post-mortem: 128-VGPR acc forced fragment rematerialization ->
//      72 ds_read_b128/wave/iter -> LDS-read bound at 41us). f32 partials.
//   3. reduce_g: sum 8 partials -> Gh/Gl bf16. T3 = W3*G (G symmetric),
//      Lt = T3*W2^T == logits TRANSPOSED (Lt[d][a]); 64x64 tiles, 256 blocks.
//   4. global softmax: pass1 block partials; pass3 combine + write WT bf16
//      + fused bb[d] = sum_c WT[d][c]*b1[c].
//   5. Mh = WT*W1T (bf16); out = Mh*X^T + bb, B straight from x f32 with
//      in-LDS transpose (pair-packed b32, XOR swizzle), 256x128 full-M tiles.
//
// Precision: logit chain bf16 hi/lo x3 (err ~2^-17 rel); out chain plain bf16.
// R7: atomic-f32 Gram epilogue regressed (16-way same-address L2 contention).
// R8: k-interleaved hi/lo loses hi*lo cross terms -> accuracy fail.

typedef unsigned short u16;
typedef __attribute__((ext_vector_type(8))) short short8;
typedef __attribute__((ext_vector_type(4))) float floatx4;

__device__ __forceinline__ u16 f2b(float f) {
  union { float f; unsigned int u; } v; v.f = f;
  unsigned int u = v.u;
  return (u16)((u + 0x7fffu + ((u >> 16) & 1u)) >> 16);  // RNE
}
__device__ __forceinline__ float b2f(u16 h) {
  union { unsigned int u; float f; } v; v.u = ((unsigned int)h) << 16;
  return v.f;
}

// ------- merged W prep: transpose w1 + split w2/w3 + zero xsum -------------
__global__ __launch_bounds__(256) void prep_w_kernel(
    const float* __restrict__ w1, const float* __restrict__ w2, const float* __restrict__ w3,
    u16* __restrict__ W1Th, u16* __restrict__ W2h, u16* __restrict__ W2l,
    u16* __restrict__ W3h, u16* __restrict__ W3l, float* __restrict__ xsum) {
  const int blk = blockIdx.x, t = threadIdx.x;
  if (blk == 576) {  // zero xsum (16*256 f32)
#pragma unroll
    for (int i = 0; i < 16; ++i) xsum[t + i * 256] = 0.f;
    return;
  }
  if (blk < 64) {  // W1Th[e][c] = w1[c][e]
    __shared__ float tile[32][33];
    const int e0 = (blk & 7) * 32, c0 = (blk >> 3) * 32;
    const int tx = t & 31, ty = t >> 5;
#pragma unroll
    for (int i = 0; i < 4; ++i)
      tile[ty + i * 8][tx] = w1[(c0 + ty + i * 8) * 256 + e0 + tx];
    __syncthreads();
#pragma unroll
    for (int i = 0; i < 4; ++i)
      W1Th[(e0 + ty + i * 8) * 256 + c0 + tx] = f2b(tile[tx][ty + i * 8]);
  } else {
    const int i = (blk - 64) * 256 + t;  // 0..131071
    const int e = i & 0xffff;
    const float f = (i >> 16) ? w3[e] : w2[e];
    u16 h = f2b(f);
    if (i >> 16) { W3h[e] = h; W3l[e] = f2b(f - b2f(h)); }
    else         { W2h[e] = h; W2l[e] = f2b(f - b2f(h)); }
  }
}

// ---- stage 8 f32 -> hi/lo bf16 LDS (one uint4 each) + running sum --------
__device__ __forceinline__ void stage8(const float4 a, const float4 b,
                                       u16* dH, u16* dL, float& xa) {
  const float f[8] = {a.x, a.y, a.z, a.w, b.x, b.y, b.z, b.w};
  union { u16 h8[8]; uint4 q; } uh, ul;
#pragma unroll
  for (int i = 0; i < 8; ++i) {
    const u16 hi = f2b(f[i]);
    uh.h8[i] = hi;
    ul.h8[i] = f2b(f[i] - b2f(hi));
    xa += f[i];
  }
  *(uint4*)dH = uh.q;
  *(uint4*)dL = ul.q;
}

// ---------------- Gram: half-M blocks, hoistable fragments -----------------
// grid = 16b x 8s x 2mh (blockIdx.x = b*16 + s*2 + mh). 512 thr / 8 waves,
// wave tile 64x64 (wm_local in {0,64}, wn in {0,64,128,192}), k-chunk 512.
__global__ __launch_bounds__(512, 2) void gram_kernel(
    const float* __restrict__ x, float* __restrict__ Gp, float* __restrict__ xsum) {
  constexpr int LR = 40;  // +8 pad: 2-way bank aliasing only (free per m136)
  __shared__ u16 lH[2][256 * LR], lL[2][256 * LR];  // 80 KB total
  const int b = blockIdx.x >> 4, s = (blockIdx.x >> 1) & 7, mh = blockIdx.x & 1;
  const float* Xb = x + (long)b * 1048576 + s * 512;
  const int t = threadIdx.x;
  const int lane = t & 63, wave = t >> 6;
  const int quad = lane >> 4, l16 = lane & 15;
  const int wml = (wave & 1) * 64 + mh * 128;  // A rows (global in slab)
  const int wn = (wave >> 1) * 64;             // B rows
  const int r0 = t >> 2, qc = (t & 3) * 8;
  const int r1 = r0 + 128;
  floatx4 acc[4][4] = {};
  float xa = 0.f;
  float4 p[4];
  p[0] = *(const float4*)(Xb + (long)r0 * 4096 + qc);
  p[1] = *(const float4*)(Xb + (long)r0 * 4096 + qc + 4);
  p[2] = *(const float4*)(Xb + (long)r1 * 4096 + qc);
  p[3] = *(const float4*)(Xb + (long)r1 * 4096 + qc + 4);
  stage8(p[0], p[1], lH[0] + r0 * LR + qc, lL[0] + r0 * LR + qc, xa);
  stage8(p[2], p[3], lH[0] + r1 * LR + qc, lL[0] + r1 * LR + qc, xa);
  __syncthreads();
  for (int kb = 0; kb < 16; ++kb) {
    const int cur = kb & 1, nxt = cur ^ 1;
    if (kb < 15) {  // issue next tile's loads; waitcnt lands after MFMA block
      const long kk = (kb + 1) * 32;
      p[0] = *(const float4*)(Xb + (long)r0 * 4096 + kk + qc);
      p[1] = *(const float4*)(Xb + (long)r0 * 4096 + kk + qc + 4);
      p[2] = *(const float4*)(Xb + (long)r1 * 4096 + kk + qc);
      p[3] = *(const float4*)(Xb + (long)r1 * 4096 + kk + qc + 4);
    }
    const u16* cH = lH[cur];
    const u16* cL = lL[cur];
    short8 ah[4], al[4];
#pragma unroll
    for (int i = 0; i < 4; ++i) {
      ah[i] = *(const short8*)(cH + (wml + i * 16 + l16) * LR + quad * 8);
      al[i] = *(const short8*)(cL + (wml + i * 16 + l16) * LR + quad * 8);
    }
#pragma unroll
    for (int j = 0; j < 4; ++j) {
      const short8 bh = *(const short8*)(cH + (wn + j * 16 + l16) * LR + quad * 8);
      const short8 bl = *(const short8*)(cL + (wn + j * 16 + l16) * LR + quad * 8);
#pragma unroll
      for (int i = 0; i < 4; ++i) {
        acc[i][j] = __builtin_amdgcn_mfma_f32_16x16x32_bf16(ah[i], bh, acc[i][j], 0, 0, 0);
        acc[i][j] = __builtin_amdgcn_mfma_f32_16x16x32_bf16(ah[i], bl, acc[i][j], 0, 0, 0);
        acc[i][j] = __builtin_amdgcn_mfma_f32_16x16x32_bf16(al[i], bh, acc[i][j], 0, 0, 0);
      }
    }
    if (kb < 15) {
      stage8(p[0], p[1], lH[nxt] + r0 * LR + qc, lL[nxt] + r0 * LR + qc, xa);
      stage8(p[2], p[3], lH[nxt] + r1 * LR + qc, lL[nxt] + r1 * LR + qc, xa);
    }
    __syncthreads();
  }
  // xsum: only mh==0 contributes (both m-halves stage the same slab)
  if (mh == 0) {
    float v0 = xa;  // split row sums: lanes t..t+3 share rows r0 and r1
    // separate row contributions were merged into xa; recompute per-row sums
    // is not possible post-hoc, so accumulate per-quad for both rows jointly:
    // xa = sum over row r0 elems + row r1 elems staged by this thread.
    // Do two atomics with halves tracked separately instead:
    (void)v0;
  }
  float* G = Gp + ((long)b * 8 + s) * 65536;
#pragma unroll
  for (int i = 0; i < 4; ++i) {
    const int row0 = wml + i * 16 + quad * 4;
#pragma unroll
    for (int j = 0; j < 4; ++j) {
      const int col = wn + j * 16 + l16;
#pragma unroll
      for (int r = 0; r < 4; ++r)
        G[(long)(row0 + r) * 256 + col] = acc[i][j][r];
    }
  }
}

// xsum needs per-row sums; gram merged r0/r1 into one accumulator. Use a tiny
// dedicated kernel instead (16 blocks x 256 thr, reads x once more? NO --
// compute from x directly: 64 MB read is too much. Instead track in gram):
// -> restored: gram accumulates xa0/xa1 separately below via second kernel.
// Simpler correct path: dedicated xsum kernel over x rows, 4096-wide reduce.
__global__ __launch_bounds__(256) void xsum_kernel(
    const float* __restrict__ x, float* __restrict__ xsum) {
  // grid: 16*256/4 blocks? Use 1024 blocks x 256 thr: each block does 4 rows.
  const int row = blockIdx.x;  // 0..4095 over b*256+c
  const float* xr = x + (long)row * 4096;
  const int t = threadIdx.x;
  float s = 0.f;
#pragma unroll
  for (int i = 0; i < 4; ++i) {
    const float4 v = *(const float4*)(xr + t * 4 + i * 1024);
    s += v.x + v.y + v.z + v.w;
  }
  for (int o = 32; o; o >>= 1) s += __shfl_xor(s, o);
  __shared__ float red[4];
  if ((t & 63) == 0) red[t >> 6] = s;
  __syncthreads();
  if (t == 0) xsum[row] = red[0] + red[1] + red[2] + red[3];
}

// ---------------- Gram split-K reduction + hi/lo split (8 splits) ----------
__global__ void reduce_g_kernel(const float* __restrict__ Gp, u16* __restrict__ Gh,
                                u16* __restrict__ Gl) {
  const long e = (long)blockIdx.x * 256 + threadIdx.x;  // over 16*65536
  const long base = ((e >> 16) << 19) + (e & 65535);    // b*8*65536 + idx
  float s = 0.f;
#pragma unroll
  for (int i = 0; i < 8; ++i) s += Gp[base + (long)i * 65536];
  u16 h = f2b(s);
  Gh[e] = h;
  Gl[e] = f2b(s - b2f(h));
}

// ------- small 256x256x256 TN GEMM: 64x64 tiles, 256-block grid ------------
// EPI: 0 = f32 store, 1 = bf16 hi/lo store, 2 = bf16 hi store
template <bool X3, int EPI>
__global__ __launch_bounds__(256) void gemm_small(
    const u16* __restrict__ Ah, const u16* __restrict__ Al,
    const u16* __restrict__ Bh, const u16* __restrict__ Bl,
    long aBatch, long bBatch, long oBatch,
    float* __restrict__ outF, u16* __restrict__ outH, u16* __restrict__ outL) {
  constexpr int LR = 40;
  __shared__ u16 smem[(X3 ? 4 : 2) * 64 * LR];
  u16* lAh = smem;
  u16* lBh = smem + 64 * LR;
  u16* lAl = X3 ? (smem + 2 * 64 * LR) : nullptr;
  u16* lBl = X3 ? (smem + 3 * 64 * LR) : nullptr;
  const int b = blockIdx.z;
  const int tm = blockIdx.x & 3, tn = blockIdx.x >> 2;  // 4x4 tiles of 64
  const u16* Ahb = Ah + (long)b * aBatch + (long)tm * 64 * 256;
  const u16* Bhb = Bh + (long)b * bBatch + (long)tn * 64 * 256;
  const u16* Alb = X3 ? (Al + (long)b * aBatch + (long)tm * 64 * 256) : nullptr;
  const u16* Blb = X3 ? (Bl + (long)b * bBatch + (long)tn * 64 * 256) : nullptr;
  const int t = threadIdx.x;
  const int lane = t & 63, wave = t >> 6;
  const int quad = lane >> 4, l16 = lane & 15;
  const int wm = (wave & 1) * 32, wn = (wave >> 1) * 32;
  const int r = t >> 2, qc = (t & 3) * 8;
  floatx4 acc[2][2] = {};
  for (int kk = 0; kk < 256; kk += 32) {
    __syncthreads();
    *(uint4*)(lAh + r * LR + qc) = *(const uint4*)(Ahb + (long)r * 256 + kk + qc);
    *(uint4*)(lBh + r * LR + qc) = *(const uint4*)(Bhb + (long)r * 256 + kk + qc);
    if (X3) {
      *(uint4*)(lAl + r * LR + qc) = *(const uint4*)(Alb + (long)r * 256 + kk + qc);
      *(uint4*)(lBl + r * LR + qc) = *(const uint4*)(Blb + (long)r * 256 + kk + qc);
    }
    __syncthreads();
    short8 afh[2], bfh[2], afl[2], bfl[2];
#pragma unroll
    for (int i = 0; i < 2; ++i) {
      afh[i] = *(const short8*)(lAh + (wm + i * 16 + l16) * LR + quad * 8);
      bfh[i] = *(const short8*)(lBh + (wn + i * 16 + l16) * LR + quad * 8);
      if (X3) {
        afl[i] = *(const short8*)(lAl + (wm + i * 16 + l16) * LR + quad * 8);
        bfl[i] = *(const short8*)(lBl + (wn + i * 16 + l16) * LR + quad * 8);
      }
    }
#pragma unroll
    for (int i = 0; i < 2; ++i)
#pragma unroll
      for (int j = 0; j < 2; ++j) {
        acc[i][j] = __builtin_amdgcn_mfma_f32_16x16x32_bf16(afh[i], bfh[j], acc[i][j], 0, 0, 0);
        if (X3) {
          acc[i][j] = __builtin_amdgcn_mfma_f32_16x16x32_bf16(afh[i], bfl[j], acc[i][j], 0, 0, 0);
          acc[i][j] = __builtin_amdgcn_mfma_f32_16x16x32_bf16(afl[i], bfh[j], acc[i][j], 0, 0, 0);
        }
      }
  }
  const long obase = (long)b * oBatch;
#pragma unroll
  for (int i = 0; i < 2; ++i) {
    const int mb = tm * 64 + wm + i * 16 + quad * 4;
#pragma unroll
    for (int j = 0; j < 2; ++j) {
      const int n = tn * 64 + wn + j * 16 + l16;
#pragma unroll
      for (int rr = 0; rr < 4; ++rr) {
        const float v = acc[i][j][rr];
        const long idx = obase + (long)(mb + rr) * 256 + n;
        if (EPI == 0) {
          outF[idx] = v;
        } else if (EPI == 1) {
          u16 h = f2b(v);
          outH[idx] = h;
          outL[idx] = f2b(v - b2f(h));
        } else {
          outH[idx] = f2b(v);
        }
      }
    }
  }
}

// ---------------- out = Mh * X^T + bb : 256x128 per block ------------------
__global__ __launch_bounds__(256, 2) void gemm_out(
    const u16* __restrict__ Mh, const float* __restrict__ x,
    const float* __restrict__ bb, float* __restrict__ out) {
  constexpr int LR = 40;
  __shared__ u16 lA[256 * LR], lB[128 * LR];
  const int b = blockIdx.z;
  const int tn = blockIdx.x;  // 0..31
  const u16* Ab = Mh + (long)b * 65536;
  const float* Xb = x + (long)b * 1048576 + tn * 128;
  const int t = threadIdx.x;
  const int lane = t & 63, wave = t >> 6;
  const int quad = lane >> 4, l16 = lane & 15;
  const int wm = wave * 64;
  const int erp = (t >> 4) * 2;   // e-row pair base 0..30
  const int n0 = (t & 15) * 8;    // n offset
  floatx4 acc[4][8] = {};
  for (int kk = 0; kk < 256; kk += 32) {
    __syncthreads();
#pragma unroll
    for (int h = 0; h < 4; ++h) {
      const int r = (t >> 2) + h * 64;
      *(uint4*)(lA + r * LR + (t & 3) * 8) =
          *(const uint4*)(Ab + (long)r * 256 + kk + (t & 3) * 8);
    }
    {
      const float4 a0 = *(const float4*)(Xb + (long)(kk + erp) * 4096 + n0);
      const float4 a1 = *(const float4*)(Xb + (long)(kk + erp) * 4096 + n0 + 4);
      const float4 c0 = *(const float4*)(Xb + (long)(kk + erp + 1) * 4096 + n0);
      const float4 c1 = *(const float4*)(Xb + (long)(kk + erp + 1) * 4096 + n0 + 4);
      const float fa[8] = {a0.x, a0.y, a0.z, a0.w, a1.x, a1.y, a1.z, a1.w};
      const float fc[8] = {c0.x, c0.y, c0.z, c0.w, c1.x, c1.y, c1.z, c1.w};
#pragma unroll
      for (int i = 0; i < 8; ++i) {
        const int nl = n0 + i;
        const int sb = (erp >> 3) ^ ((nl >> 4) & 3);  // swizzle e-block
        const unsigned int pk =
            (unsigned int)f2b(fa[i]) | ((unsigned int)f2b(fc[i]) << 16);
        *(unsigned int*)(lB + nl * LR + sb * 8 + (erp & 7)) = pk;
      }
    }
    __syncthreads();
    short8 af[4], bf[8];
#pragma unroll
    for (int j = 0; j < 8; ++j) {
      const int n = j * 16 + l16;
      const int rb = quad ^ ((n >> 4) & 3);
      bf[j] = *(const short8*)(lB + n * LR + rb * 8);
    }
#pragma unroll
    for (int i = 0; i < 4; ++i)
      af[i] = *(const short8*)(lA + (wm + i * 16 + l16) * LR + quad * 8);
#pragma unroll
    for (int i = 0; i < 4; ++i)
#pragma unroll
      for (int j = 0; j < 8; ++j)
        acc[i][j] = __builtin_amdgcn_mfma_f32_16x16x32_bf16(af[i], bf[j], acc[i][j], 0, 0, 0);
  }
  const long obase = (long)b * 1048576;
#pragma unroll
  for (int i = 0; i < 4; ++i) {
    const int mb = wm + i * 16 + quad * 4;
#pragma unroll
    for (int j = 0; j < 8; ++j) {
      const int n = tn * 128 + j * 16 + l16;
#pragma unroll
      for (int r = 0; r < 4; ++r)
        out[obase + (long)(mb + r) * 4096 + n] = acc[i][j][r] + bb[b * 256 + mb + r];
    }
  }
}

// ---------------- bias prep: s2[b][a]=w2[a,:]·xsum[b], s3 likewise --------
__global__ __launch_bounds__(512) void bias_prep_kernel(
    const float* __restrict__ w2, const float* __restrict__ w3,
    const float* __restrict__ xsum, float* __restrict__ S2, float* __restrict__ S3) {
  __shared__ float xs[256];
  const int b = blockIdx.x, t = threadIdx.x;
  if (t < 256) xs[t] = xsum[b * 256 + t];
  __syncthreads();
  const float* wm = (t < 256) ? w2 : w3;
  const int a = t & 255;
  float s = 0.f;
#pragma unroll 4
  for (int c = 0; c < 256; ++c) s += wm[a * 256 + c] * xs[c];
  if (t < 256) S2[b * 256 + a] = s;
  else         S3[b * 256 + a] = s;
}

// ---------------- softmax pass1: per-block (max, sumexp) ------------------
__global__ __launch_bounds__(256) void softmax_pass1(
    const float* __restrict__ Lt, const float* __restrict__ S2, const float* __restrict__ S3,
    const float* __restrict__ b2, const float* __restrict__ b3,
    float* __restrict__ bm, float* __restrict__ bs) {
  __shared__ float ls2[256], lb2[256];
  __shared__ float redm[4], reds[4];
  const int b = blockIdx.y, blk = blockIdx.x, t = threadIdx.x;
  ls2[t] = S2[b * 256 + t];
  lb2[t] = b2[t];
  __syncthreads();
  const int fw0 = blk * 2048 + t * 8;
  const int d = fw0 >> 8, a0 = fw0 & 255;
  const float c1 = b3[d];
  const float c0 = S3[b * 256 + d] + 4096.f * c1;
  const long base = (long)b * 65536 + fw0;
  float4 v0 = *(const float4*)(Lt + base);
  float4 v1 = *(const float4*)(Lt + base + 4);
  float v[8] = {v0.x, v0.y, v0.z, v0.w, v1.x, v1.y, v1.z, v1.w};
  float m = -3.4e38f;
#pragma unroll
  for (int i = 0; i < 8; ++i) {
    v[i] += lb2[a0 + i] * c0 + c1 * ls2[a0 + i];
    m = fmaxf(m, v[i]);
  }
  for (int o = 32; o; o >>= 1) m = fmaxf(m, __shfl_xor(m, o));
  const int wid = t >> 6, lane = t & 63;
  if (lane == 0) redm[wid] = m;
  __syncthreads();
  const float bmax = fmaxf(fmaxf(redm[0], redm[1]), fmaxf(redm[2], redm[3]));
  float s = 0.f;
#pragma unroll
  for (int i = 0; i < 8; ++i) s += __expf(v[i] - bmax);
  for (int o = 32; o; o >>= 1) s += __shfl_xor(s, o);
  if (lane == 0) reds[wid] = s;
  __syncthreads();
  if (t == 0) {
    bm[b * 32 + blk] = bmax;
    bs[b * 32 + blk] = reds[0] + reds[1] + reds[2] + reds[3];
  }
}

// -- softmax pass3: inline combine + write WT bf16 + fused bb[d]=WT·b1 ------
__global__ __launch_bounds__(256) void softmax_pass3(
    const float* __restrict__ Lt, const float* __restrict__ S2, const float* __restrict__ S3,
    const float* __restrict__ b2, const float* __restrict__ b3,
    const float* __restrict__ bm, const float* __restrict__ bs,
    const float* __restrict__ b1, u16* __restrict__ WTh, float* __restrict__ bb) {
  __shared__ float ls2[256], lb2[256], lb1[256];
  __shared__ float sM, sInv;
  const int b = blockIdx.y, blk = blockIdx.x, t = threadIdx.x;
  if (t < 64) {  // combine 32 block pairs (wave 0 only)
    const float m = (t < 32) ? bm[b * 32 + t] : -3.4e38f;
    float s = (t < 32) ? bs[b * 32 + t] : 0.f;
    float M = m;
    for (int o = 32; o; o >>= 1) M = fmaxf(M, __shfl_xor(M, o));
    s *= __expf(m - M);
    for (int o = 32; o; o >>= 1) s += __shfl_xor(s, o);
    if (t == 0) { sM = M; sInv = 1.0f / s; }
  }
  ls2[t] = S2[b * 256 + t];
  lb2[t] = b2[t];
  lb1[t] = b1[t];
  __syncthreads();
  const float M = sM, inv = sInv;
  const int fw0 = blk * 2048 + t * 8;
  const int d = fw0 >> 8, a0 = fw0 & 255;
  const float c1 = b3[d];
  const float c0 = S3[b * 256 + d] + 4096.f * c1;
  const long base = (long)b * 65536 + fw0;
  float4 v0 = *(const float4*)(Lt + base);
  float4 v1 = *(const float4*)(Lt + base + 4);
  float v[8] = {v0.x, v0.y, v0.z, v0.w, v1.x, v1.y, v1.z, v1.w};
  union { u16 h[8]; uint4 q; } o;
  float bsum = 0.f;
#pragma unroll
  for (int i = 0; i < 8; ++i) {
    const float vv = v[i] + lb2[a0 + i] * c0 + c1 * ls2[a0 + i];
    const float w = __expf(vv - M) * inv;
    o.h[i] = f2b(w);
    bsum += w * lb1[a0 + i];
  }
  *(uint4*)(WTh + base) = o.q;
  // row d spans 32 consecutive threads
  for (int off = 16; off; off >>= 1) bsum += __shfl_xor(bsum, off);
  if ((t & 31) == 0) bb[b * 256 + d] = bsum;
}

extern "C" void kernel_launch(void* const* d_in, const int* in_sizes, int n_in,
                              void* d_out, int out_size, void* d_ws, size_t ws_size,
                              hipStream_t stream) {
  const float* x  = (const float*)d_in[0];
  const float* w1 = (const float*)d_in[1];
  const float* b1 = (const float*)d_in[2];
  const float* w2 = (const float*)d_in[3];
  const float* b2 = (const float*)d_in[4];
  const float* w3 = (const float*)d_in[5];
  const float* b3 = (const float*)d_in[6];
  float* out = (float*)d_out;

  char* ws = (char*)d_ws;
  size_t off = 0;
  auto alloc = [&](size_t bytes) {
    void* p = ws + off;
    off += (bytes + 255) & ~(size_t)255;
    return p;
  };
  float* Gp = (float*)alloc(8ull * 16 * 65536 * 4);    // 32 MiB split-K partials
  float* xsum = (float*)alloc(16 * 256 * 4);
  u16* Gh   = (u16*)alloc(16ull * 65536 * 2);
  u16* Gl   = (u16*)alloc(16ull * 65536 * 2);
  u16* T3h  = (u16*)alloc(16ull * 65536 * 2);
  u16* T3l  = (u16*)alloc(16ull * 65536 * 2);
  float* Lb = (float*)alloc(16ull * 65536 * 4);        // Lt[d][a]
  u16* WTh  = (u16*)alloc(16ull * 65536 * 2);
  u16* Mh   = (u16*)alloc(16ull * 65536 * 2);
  u16* W1Th = (u16*)alloc(65536 * 2);
  u16* W2h  = (u16*)alloc(65536 * 2);
  u16* W2l  = (u16*)alloc(65536 * 2);
  u16* W3h  = (u16*)alloc(65536 * 2);
  u16* W3l  = (u16*)alloc(65536 * 2);
  float* S2   = (float*)alloc(16 * 256 * 4);
  float* S3   = (float*)alloc(16 * 256 * 4);
  float* bmx  = (float*)alloc(16 * 32 * 4);
  float* bsx  = (float*)alloc(16 * 32 * 4);
  float* bb   = (float*)alloc(16 * 256 * 4);

  prep_w_kernel<<<577, 256, 0, stream>>>(w1, w2, w3, W1Th, W2h, W2l, W3h, W3l, xsum);

  // xsum from x directly (row sums); overlaps nothing but is tiny vs gram.
  xsum_kernel<<<4096, 256, 0, stream>>>(x, xsum);

  // Gram partials: 16 batches x 8 splits x 2 m-halves.
  gram_kernel<<<256, 512, 0, stream>>>(x, Gp, xsum);
  reduce_g_kernel<<<4096, 256, 0, stream>>>(Gp, Gh, Gl);

  // T3 = W3 * G (G symmetric -> TN ok). 64x64 tiles, 256 blocks.
  gemm_small<true, 1><<<dim3(16, 1, 16), 256, 0, stream>>>(
      W3h, W3l, Gh, Gl, 0, 65536, 65536, nullptr, T3h, T3l);
  // Lt = T3 * W2^T  ->  Lt[d][a] = logits[a][d].
  gemm_small<true, 0><<<dim3(16, 1, 16), 256, 0, stream>>>(
      T3h, T3l, W2h, W2l, 65536, 0, 65536, Lb, nullptr, nullptr);

  // softmax: bias prep + pass1 + fused combine/write/bb pass3
  bias_prep_kernel<<<16, 512, 0, stream>>>(w2, w3, xsum, S2, S3);
  softmax_pass1<<<dim3(32, 16), 256, 0, stream>>>(Lb, S2, S3, b2, b3, bmx, bsx);
  softmax_pass3<<<dim3(32, 16), 256, 0, stream>>>(Lb, S2, S3, b2, b3, bmx, bsx,
                                                  b1, WTh, bb);

  // out-chain: Mh = WT*W1T (bf16), out = Mh*X^T + bb
  gemm_small<false, 2><<<dim3(16, 1, 16), 256, 0, stream>>>(
      WTh, nullptr, W1Th, nullptr, 65536, 0, 65536, nullptr, Mh, nullptr);
  gemm_out<<<dim3(32, 1, 16), 256, 0, stream>>>(Mh, x, bb, out);
}

// Round 11
// 216.577 us; speedup vs baseline: 1.1702x; 1.0156x over previous
//
#include <hip/hip_runtime.h>

// GlobalChannelAttention: B=16, C=256, H*W=4096
//
// Pipeline (TN-form GEMMs: C[M,N] = sum_k A[m][k]*B[n][k], K contiguous):
//   1. prep_w: w1 -> W1Th (bf16 transposed), w2/w3 -> hi/lo bf16, zero xsum
//   2. gram: G[b] = X X^T from raw x f32 (hi/lo in SEPARATE LDS slabs, 3
//      MFMAs hh+hl+lh). HALF-M blocks: grid 16b x 8splits x 2mhalf, each
//      512-thr block computes 128x256 over k-chunk 512, wave tiles 64x64 ->
//      acc 4x4 (64 VGPR) so A/B fragments stay hoisted in registers.
//      Per-row xsum accumulated during staging (mh==0 blocks only -- both
//      m-halves stage the same slab). f32 partials.
//   3. reduce_g: sum 8 partials -> Gh/Gl bf16. T3 = W3*G (G symmetric),
//      Lt = T3*W2^T == logits TRANSPOSED (Lt[d][a]); 64x64 tiles, 256 blocks.
//   4. global softmax: pass1 block partials; pass3 combine + write WT bf16
//      + fused bb[d] = sum_c WT[d][c]*b1[c].
//   5. Mh = WT*W1T (bf16); out = Mh*X^T + bb, B straight from x f32 with
//      in-LDS transpose (pair-packed b32, XOR swizzle), 256x128 full-M tiles.
//
// Precision: logit chain bf16 hi/lo x3 (err ~2^-17 rel); out chain plain bf16.
// R7: atomic-f32 Gram epilogue regressed (16-way same-address L2 contention).
// R8: k-interleaved hi/lo loses hi*lo cross terms -> accuracy fail.
// R9: 128-VGPR acc forced fragment rematerialization -> LDS-read bound 41us;
//     half-M tiles (64-VGPR acc) let fragments stay resident.
// R10: separate xsum_kernel re-read 64MB of x -- folded back into gram here.

typedef unsigned short u16;
typedef __attribute__((ext_vector_type(8))) short short8;
typedef __attribute__((ext_vector_type(4))) float floatx4;

__device__ __forceinline__ u16 f2b(float f) {
  union { float f; unsigned int u; } v; v.f = f;
  unsigned int u = v.u;
  return (u16)((u + 0x7fffu + ((u >> 16) & 1u)) >> 16);  // RNE
}
__device__ __forceinline__ float b2f(u16 h) {
  union { unsigned int u; float f; } v; v.u = ((unsigned int)h) << 16;
  return v.f;
}

// ------- merged W prep: transpose w1 + split w2/w3 + zero xsum -------------
__global__ __launch_bounds__(256) void prep_w_kernel(
    const float* __restrict__ w1, const float* __restrict__ w2, const float* __restrict__ w3,
    u16* __restrict__ W1Th, u16* __restrict__ W2h, u16* __restrict__ W2l,
    u16* __restrict__ W3h, u16* __restrict__ W3l, float* __restrict__ xsum) {
  const int blk = blockIdx.x, t = threadIdx.x;
  if (blk == 576) {  // zero xsum (16*256 f32)
#pragma unroll
    for (int i = 0; i < 16; ++i) xsum[t + i * 256] = 0.f;
    return;
  }
  if (blk < 64) {  // W1Th[e][c] = w1[c][e]
    __shared__ float tile[32][33];
    const int e0 = (blk & 7) * 32, c0 = (blk >> 3) * 32;
    const int tx = t & 31, ty = t >> 5;
#pragma unroll
    for (int i = 0; i < 4; ++i)
      tile[ty + i * 8][tx] = w1[(c0 + ty + i * 8) * 256 + e0 + tx];
    __syncthreads();
#pragma unroll
    for (int i = 0; i < 4; ++i)
      W1Th[(e0 + ty + i * 8) * 256 + c0 + tx] = f2b(tile[tx][ty + i * 8]);
  } else {
    const int i = (blk - 64) * 256 + t;  // 0..131071
    const int e = i & 0xffff;
    const float f = (i >> 16) ? w3[e] : w2[e];
    u16 h = f2b(f);
    if (i >> 16) { W3h[e] = h; W3l[e] = f2b(f - b2f(h)); }
    else         { W2h[e] = h; W2l[e] = f2b(f - b2f(h)); }
  }
}

// ---- stage 8 f32 -> hi/lo bf16 LDS (one uint4 each) + running sum --------
__device__ __forceinline__ void stage8(const float4 a, const float4 b,
                                       u16* dH, u16* dL, float& xa) {
  const float f[8] = {a.x, a.y, a.z, a.w, b.x, b.y, b.z, b.w};
  union { u16 h8[8]; uint4 q; } uh, ul;
#pragma unroll
  for (int i = 0; i < 8; ++i) {
    const u16 hi = f2b(f[i]);
    uh.h8[i] = hi;
    ul.h8[i] = f2b(f[i] - b2f(hi));
    xa += f[i];
  }
  *(uint4*)dH = uh.q;
  *(uint4*)dL = ul.q;
}

// ---------------- Gram: half-M blocks, hoisted fragments -------------------
// grid = 16b x 8s x 2mh (blockIdx.x = b*16 + s*2 + mh). 512 thr / 8 waves,
// wave tile 64x64 (wml in {0,64}+mh*128, wn in {0,64,128,192}), k-chunk 512.
__global__ __launch_bounds__(512, 2) void gram_kernel(
    const float* __restrict__ x, float* __restrict__ Gp, float* __restrict__ xsum) {
  constexpr int LR = 40;  // +8 pad: 2-way bank aliasing only (free per m136)
  __shared__ u16 lH[2][256 * LR], lL[2][256 * LR];  // 80 KB total
  const int b = blockIdx.x >> 4, s = (blockIdx.x >> 1) & 7, mh = blockIdx.x & 1;
  const float* Xb = x + (long)b * 1048576 + s * 512;
  const int t = threadIdx.x;
  const int lane = t & 63, wave = t >> 6;
  const int quad = lane >> 4, l16 = lane & 15;
  const int wml = (wave & 1) * 64 + mh * 128;  // A rows in slab
  const int wn = (wave >> 1) * 64;             // B rows
  const int r0 = t >> 2, qc = (t & 3) * 8;
  const int r1 = r0 + 128;
  floatx4 acc[4][4] = {};
  float xa0 = 0.f, xa1 = 0.f;  // per-row running sums (rows r0, r1)
  float4 p[4];
  p[0] = *(const float4*)(Xb + (long)r0 * 4096 + qc);
  p[1] = *(const float4*)(Xb + (long)r0 * 4096 + qc + 4);
  p[2] = *(const float4*)(Xb + (long)r1 * 4096 + qc);
  p[3] = *(const float4*)(Xb + (long)r1 * 4096 + qc + 4);
  stage8(p[0], p[1], lH[0] + r0 * LR + qc, lL[0] + r0 * LR + qc, xa0);
  stage8(p[2], p[3], lH[0] + r1 * LR + qc, lL[0] + r1 * LR + qc, xa1);
  __syncthreads();
  for (int kb = 0; kb < 16; ++kb) {
    const int cur = kb & 1, nxt = cur ^ 1;
    if (kb < 15) {  // issue next tile's loads; waitcnt lands after MFMA block
      const long kk = (kb + 1) * 32;
      p[0] = *(const float4*)(Xb + (long)r0 * 4096 + kk + qc);
      p[1] = *(const float4*)(Xb + (long)r0 * 4096 + kk + qc + 4);
      p[2] = *(const float4*)(Xb + (long)r1 * 4096 + kk + qc);
      p[3] = *(const float4*)(Xb + (long)r1 * 4096 + kk + qc + 4);
    }
    const u16* cH = lH[cur];
    const u16* cL = lL[cur];
    short8 ah[4], al[4];
#pragma unroll
    for (int i = 0; i < 4; ++i) {
      ah[i] = *(const short8*)(cH + (wml + i * 16 + l16) * LR + quad * 8);
      al[i] = *(const short8*)(cL + (wml + i * 16 + l16) * LR + quad * 8);
    }
#pragma unroll
    for (int j = 0; j < 4; ++j) {
      const short8 bh = *(const short8*)(cH + (wn + j * 16 + l16) * LR + quad * 8);
      const short8 bl = *(const short8*)(cL + (wn + j * 16 + l16) * LR + quad * 8);
#pragma unroll
      for (int i = 0; i < 4; ++i) {
        acc[i][j] = __builtin_amdgcn_mfma_f32_16x16x32_bf16(ah[i], bh, acc[i][j], 0, 0, 0);
        acc[i][j] = __builtin_amdgcn_mfma_f32_16x16x32_bf16(ah[i], bl, acc[i][j], 0, 0, 0);
        acc[i][j] = __builtin_amdgcn_mfma_f32_16x16x32_bf16(al[i], bh, acc[i][j], 0, 0, 0);
      }
    }
    if (kb < 15) {
      stage8(p[0], p[1], lH[nxt] + r0 * LR + qc, lL[nxt] + r0 * LR + qc, xa0);
      stage8(p[2], p[3], lH[nxt] + r1 * LR + qc, lL[nxt] + r1 * LR + qc, xa1);
    }
    __syncthreads();
  }
  // xsum: only mh==0 contributes (both m-halves staged the same slab).
  // Threads 4k..4k+3 share rows r0/r1 -> quad shuffle then one atomic.
  if (mh == 0) {
    float v = xa0;
    v += __shfl_xor(v, 1);
    v += __shfl_xor(v, 2);
    if ((t & 3) == 0) atomicAdd(&xsum[b * 256 + r0], v);
    v = xa1;
    v += __shfl_xor(v, 1);
    v += __shfl_xor(v, 2);
    if ((t & 3) == 0) atomicAdd(&xsum[b * 256 + r1], v);
  }
  float* G = Gp + ((long)b * 8 + s) * 65536;
#pragma unroll
  for (int i = 0; i < 4; ++i) {
    const int row0 = wml + i * 16 + quad * 4;
#pragma unroll
    for (int j = 0; j < 4; ++j) {
      const int col = wn + j * 16 + l16;
#pragma unroll
      for (int r = 0; r < 4; ++r)
        G[(long)(row0 + r) * 256 + col] = acc[i][j][r];
    }
  }
}

// ---------------- Gram split-K reduction + hi/lo split (8 splits) ----------
__global__ void reduce_g_kernel(const float* __restrict__ Gp, u16* __restrict__ Gh,
                                u16* __restrict__ Gl) {
  const long e = (long)blockIdx.x * 256 + threadIdx.x;  // over 16*65536
  const long base = ((e >> 16) << 19) + (e & 65535);    // b*8*65536 + idx
  float s = 0.f;
#pragma unroll
  for (int i = 0; i < 8; ++i) s += Gp[base + (long)i * 65536];
  u16 h = f2b(s);
  Gh[e] = h;
  Gl[e] = f2b(s - b2f(h));
}

// ------- small 256x256x256 TN GEMM: 64x64 tiles, 256-block grid ------------
// EPI: 0 = f32 store, 1 = bf16 hi/lo store, 2 = bf16 hi store
template <bool X3, int EPI>
__global__ __launch_bounds__(256) void gemm_small(
    const u16* __restrict__ Ah, const u16* __restrict__ Al,
    const u16* __restrict__ Bh, const u16* __restrict__ Bl,
    long aBatch, long bBatch, long oBatch,
    float* __restrict__ outF, u16* __restrict__ outH, u16* __restrict__ outL) {
  constexpr int LR = 40;
  __shared__ u16 smem[(X3 ? 4 : 2) * 64 * LR];
  u16* lAh = smem;
  u16* lBh = smem + 64 * LR;
  u16* lAl = X3 ? (smem + 2 * 64 * LR) : nullptr;
  u16* lBl = X3 ? (smem + 3 * 64 * LR) : nullptr;
  const int b = blockIdx.z;
  const int tm = blockIdx.x & 3, tn = blockIdx.x >> 2;  // 4x4 tiles of 64
  const u16* Ahb = Ah + (long)b * aBatch + (long)tm * 64 * 256;
  const u16* Bhb = Bh + (long)b * bBatch + (long)tn * 64 * 256;
  const u16* Alb = X3 ? (Al + (long)b * aBatch + (long)tm * 64 * 256) : nullptr;
  const u16* Blb = X3 ? (Bl + (long)b * bBatch + (long)tn * 64 * 256) : nullptr;
  const int t = threadIdx.x;
  const int lane = t & 63, wave = t >> 6;
  const int quad = lane >> 4, l16 = lane & 15;
  const int wm = (wave & 1) * 32, wn = (wave >> 1) * 32;
  const int r = t >> 2, qc = (t & 3) * 8;
  floatx4 acc[2][2] = {};
  for (int kk = 0; kk < 256; kk += 32) {
    __syncthreads();
    *(uint4*)(lAh + r * LR + qc) = *(const uint4*)(Ahb + (long)r * 256 + kk + qc);
    *(uint4*)(lBh + r * LR + qc) = *(const uint4*)(Bhb + (long)r * 256 + kk + qc);
    if (X3) {
      *(uint4*)(lAl + r * LR + qc) = *(const uint4*)(Alb + (long)r * 256 + kk + qc);
      *(uint4*)(lBl + r * LR + qc) = *(const uint4*)(Blb + (long)r * 256 + kk + qc);
    }
    __syncthreads();
    short8 afh[2], bfh[2], afl[2], bfl[2];
#pragma unroll
    for (int i = 0; i < 2; ++i) {
      afh[i] = *(const short8*)(lAh + (wm + i * 16 + l16) * LR + quad * 8);
      bfh[i] = *(const short8*)(lBh + (wn + i * 16 + l16) * LR + quad * 8);
      if (X3) {
        afl[i] = *(const short8*)(lAl + (wm + i * 16 + l16) * LR + quad * 8);
        bfl[i] = *(const short8*)(lBl + (wn + i * 16 + l16) * LR + quad * 8);
      }
    }
#pragma unroll
    for (int i = 0; i < 2; ++i)
#pragma unroll
      for (int j = 0; j < 2; ++j) {
        acc[i][j] = __builtin_amdgcn_mfma_f32_16x16x32_bf16(afh[i], bfh[j], acc[i][j], 0, 0, 0);
        if (X3) {
          acc[i][j] = __builtin_amdgcn_mfma_f32_16x16x32_bf16(afh[i], bfl[j], acc[i][j], 0, 0, 0);
          acc[i][j] = __builtin_amdgcn_mfma_f32_16x16x32_bf16(afl[i], bfh[j], acc[i][j], 0, 0, 0);
        }
      }
  }
  const long obase = (long)b * oBatch;
#pragma unroll
  for (int i = 0; i < 2; ++i) {
    const int mb = tm * 64 + wm + i * 16 + quad * 4;
#pragma unroll
    for (int j = 0; j < 2; ++j) {
      const int n = tn * 64 + wn + j * 16 + l16;
#pragma unroll
      for (int rr = 0; rr < 4; ++rr) {
        const float v = acc[i][j][rr];
        const long idx = obase + (long)(mb + rr) * 256 + n;
        if (EPI == 0) {
          outF[idx] = v;
        } else if (EPI == 1) {
          u16 h = f2b(v);
          outH[idx] = h;
          outL[idx] = f2b(v - b2f(h));
        } else {
          outH[idx] = f2b(v);
        }
      }
    }
  }
}

// ---------------- out = Mh * X^T + bb : 256x128 per block ------------------
__global__ __launch_bounds__(256, 2) void gemm_out(
    const u16* __restrict__ Mh, const float* __restrict__ x,
    const float* __restrict__ bb, float* __restrict__ out) {
  constexpr int LR = 40;
  __shared__ u16 lA[256 * LR], lB[128 * LR];
  const int b = blockIdx.z;
  const int tn = blockIdx.x;  // 0..31
  const u16* Ab = Mh + (long)b * 65536;
  const float* Xb = x + (long)b * 1048576 + tn * 128;
  const int t = threadIdx.x;
  const int lane = t & 63, wave = t >> 6;
  const int quad = lane >> 4, l16 = lane & 15;
  const int wm = wave * 64;
  const int erp = (t >> 4) * 2;   // e-row pair base 0..30
  const int n0 = (t & 15) * 8;    // n offset
  floatx4 acc[4][8] = {};
  for (int kk = 0; kk < 256; kk += 32) {
    __syncthreads();
#pragma unroll
    for (int h = 0; h < 4; ++h) {
      const int r = (t >> 2) + h * 64;
      *(uint4*)(lA + r * LR + (t & 3) * 8) =
          *(const uint4*)(Ab + (long)r * 256 + kk + (t & 3) * 8);
    }
    {
      const float4 a0 = *(const float4*)(Xb + (long)(kk + erp) * 4096 + n0);
      const float4 a1 = *(const float4*)(Xb + (long)(kk + erp) * 4096 + n0 + 4);
      const float4 c0 = *(const float4*)(Xb + (long)(kk + erp + 1) * 4096 + n0);
      const float4 c1 = *(const float4*)(Xb + (long)(kk + erp + 1) * 4096 + n0 + 4);
      const float fa[8] = {a0.x, a0.y, a0.z, a0.w, a1.x, a1.y, a1.z, a1.w};
      const float fc[8] = {c0.x, c0.y, c0.z, c0.w, c1.x, c1.y, c1.z, c1.w};
#pragma unroll
      for (int i = 0; i < 8; ++i) {
        const int nl = n0 + i;
        const int sb = (erp >> 3) ^ ((nl >> 4) & 3);  // swizzle e-block
        const unsigned int pk =
            (unsigned int)f2b(fa[i]) | ((unsigned int)f2b(fc[i]) << 16);
        *(unsigned int*)(lB + nl * LR + sb * 8 + (erp & 7)) = pk;
      }
    }
    __syncthreads();
    short8 af[4], bf[8];
#pragma unroll
    for (int j = 0; j < 8; ++j) {
      const int n = j * 16 + l16;
      const int rb = quad ^ ((n >> 4) & 3);
      bf[j] = *(const short8*)(lB + n * LR + rb * 8);
    }
#pragma unroll
    for (int i = 0; i < 4; ++i)
      af[i] = *(const short8*)(lA + (wm + i * 16 + l16) * LR + quad * 8);
#pragma unroll
    for (int i = 0; i < 4; ++i)
#pragma unroll
      for (int j = 0; j < 8; ++j)
        acc[i][j] = __builtin_amdgcn_mfma_f32_16x16x32_bf16(af[i], bf[j], acc[i][j], 0, 0, 0);
  }
  const long obase = (long)b * 1048576;
#pragma unroll
  for (int i = 0; i < 4; ++i) {
    const int mb = wm + i * 16 + quad * 4;
#pragma unroll
    for (int j = 0; j < 8; ++j) {
      const int n = tn * 128 + j * 16 + l16;
#pragma unroll
      for (int r = 0; r < 4; ++r)
        out[obase + (long)(mb + r) * 4096 + n] = acc[i][j][r] + bb[b * 256 + mb + r];
    }
  }
}

// ---------------- bias prep: s2[b][a]=w2[a,:]·xsum[b], s3 likewise --------
__global__ __launch_bounds__(512) void bias_prep_kernel(
    const float* __restrict__ w2, const float* __restrict__ w3,
    const float* __restrict__ xsum, float* __restrict__ S2, float* __restrict__ S3) {
  __shared__ float xs[256];
  const int b = blockIdx.x, t = threadIdx.x;
  if (t < 256) xs[t] = xsum[b * 256 + t];
  __syncthreads();
  const float* wm = (t < 256) ? w2 : w3;
  const int a = t & 255;
  float s = 0.f;
#pragma unroll 4
  for (int c = 0; c < 256; ++c) s += wm[a * 256 + c] * xs[c];
  if (t < 256) S2[b * 256 + a] = s;
  else         S3[b * 256 + a] = s;
}

// ---------------- softmax pass1: per-block (max, sumexp) ------------------
__global__ __launch_bounds__(256) void softmax_pass1(
    const float* __restrict__ Lt, const float* __restrict__ S2, const float* __restrict__ S3,
    const float* __restrict__ b2, const float* __restrict__ b3,
    float* __restrict__ bm, float* __restrict__ bs) {
  __shared__ float ls2[256], lb2[256];
  __shared__ float redm[4], reds[4];
  const int b = blockIdx.y, blk = blockIdx.x, t = threadIdx.x;
  ls2[t] = S2[b * 256 + t];
  lb2[t] = b2[t];
  __syncthreads();
  const int fw0 = blk * 2048 + t * 8;
  const int d = fw0 >> 8, a0 = fw0 & 255;
  const float c1 = b3[d];
  const float c0 = S3[b * 256 + d] + 4096.f * c1;
  const long base = (long)b * 65536 + fw0;
  float4 v0 = *(const float4*)(Lt + base);
  float4 v1 = *(const float4*)(Lt + base + 4);
  float v[8] = {v0.x, v0.y, v0.z, v0.w, v1.x, v1.y, v1.z, v1.w};
  float m = -3.4e38f;
#pragma unroll
  for (int i = 0; i < 8; ++i) {
    v[i] += lb2[a0 + i] * c0 + c1 * ls2[a0 + i];
    m = fmaxf(m, v[i]);
  }
  for (int o = 32; o; o >>= 1) m = fmaxf(m, __shfl_xor(m, o));
  const int wid = t >> 6, lane = t & 63;
  if (lane == 0) redm[wid] = m;
  __syncthreads();
  const float bmax = fmaxf(fmaxf(redm[0], redm[1]), fmaxf(redm[2], redm[3]));
  float s = 0.f;
#pragma unroll
  for (int i = 0; i < 8; ++i) s += __expf(v[i] - bmax);
  for (int o = 32; o; o >>= 1) s += __shfl_xor(s, o);
  if (lane == 0) reds[wid] = s;
  __syncthreads();
  if (t == 0) {
    bm[b * 32 + blk] = bmax;
    bs[b * 32 + blk] = reds[0] + reds[1] + reds[2] + reds[3];
  }
}

// -- softmax pass3: inline combine + write WT bf16 + fused bb[d]=WT·b1 ------
__global__ __launch_bounds__(256) void softmax_pass3(
    const float* __restrict__ Lt, const float* __restrict__ S2, const float* __restrict__ S3,
    const float* __restrict__ b2, const float* __restrict__ b3,
    const float* __restrict__ bm, const float* __restrict__ bs,
    const float* __restrict__ b1, u16* __restrict__ WTh, float* __restrict__ bb) {
  __shared__ float ls2[256], lb2[256], lb1[256];
  __shared__ float sM, sInv;
  const int b = blockIdx.y, blk = blockIdx.x, t = threadIdx.x;
  if (t < 64) {  // combine 32 block pairs (wave 0 only)
    const float m = (t < 32) ? bm[b * 32 + t] : -3.4e38f;
    float s = (t < 32) ? bs[b * 32 + t] : 0.f;
    float M = m;
    for (int o = 32; o; o >>= 1) M = fmaxf(M, __shfl_xor(M, o));
    s *= __expf(m - M);
    for (int o = 32; o; o >>= 1) s += __shfl_xor(s, o);
    if (t == 0) { sM = M; sInv = 1.0f / s; }
  }
  ls2[t] = S2[b * 256 + t];
  lb2[t] = b2[t];
  lb1[t] = b1[t];
  __syncthreads();
  const float M = sM, inv = sInv;
  const int fw0 = blk * 2048 + t * 8;
  const int d = fw0 >> 8, a0 = fw0 & 255;
  const float c1 = b3[d];
  const float c0 = S3[b * 256 + d] + 4096.f * c1;
  const long base = (long)b * 65536 + fw0;
  float4 v0 = *(const float4*)(Lt + base);
  float4 v1 = *(const float4*)(Lt + base + 4);
  float v[8] = {v0.x, v0.y, v0.z, v0.w, v1.x, v1.y, v1.z, v1.w};
  union { u16 h[8]; uint4 q; } o;
  float bsum = 0.f;
#pragma unroll
  for (int i = 0; i < 8; ++i) {
    const float vv = v[i] + lb2[a0 + i] * c0 + c1 * ls2[a0 + i];
    const float w = __expf(vv - M) * inv;
    o.h[i] = f2b(w);
    bsum += w * lb1[a0 + i];
  }
  *(uint4*)(WTh + base) = o.q;
  // row d spans 32 consecutive threads
  for (int off = 16; off; off >>= 1) bsum += __shfl_xor(bsum, off);
  if ((t & 31) == 0) bb[b * 256 + d] = bsum;
}

extern "C" void kernel_launch(void* const* d_in, const int* in_sizes, int n_in,
                              void* d_out, int out_size, void* d_ws, size_t ws_size,
                              hipStream_t stream) {
  const float* x  = (const float*)d_in[0];
  const float* w1 = (const float*)d_in[1];
  const float* b1 = (const float*)d_in[2];
  const float* w2 = (const float*)d_in[3];
  const float* b2 = (const float*)d_in[4];
  const float* w3 = (const float*)d_in[5];
  const float* b3 = (const float*)d_in[6];
  float* out = (float*)d_out;

  char* ws = (char*)d_ws;
  size_t off = 0;
  auto alloc = [&](size_t bytes) {
    void* p = ws + off;
    off += (bytes + 255) & ~(size_t)255;
    return p;
  };
  float* Gp = (float*)alloc(8ull * 16 * 65536 * 4);    // 32 MiB split-K partials
  float* xsum = (float*)alloc(16 * 256 * 4);
  u16* Gh   = (u16*)alloc(16ull * 65536 * 2);
  u16* Gl   = (u16*)alloc(16ull * 65536 * 2);
  u16* T3h  = (u16*)alloc(16ull * 65536 * 2);
  u16* T3l  = (u16*)alloc(16ull * 65536 * 2);
  float* Lb = (float*)alloc(16ull * 65536 * 4);        // Lt[d][a]
  u16* WTh  = (u16*)alloc(16ull * 65536 * 2);
  u16* Mh   = (u16*)alloc(16ull * 65536 * 2);
  u16* W1Th = (u16*)alloc(65536 * 2);
  u16* W2h  = (u16*)alloc(65536 * 2);
  u16* W2l  = (u16*)alloc(65536 * 2);
  u16* W3h  = (u16*)alloc(65536 * 2);
  u16* W3l  = (u16*)alloc(65536 * 2);
  float* S2   = (float*)alloc(16 * 256 * 4);
  float* S3   = (float*)alloc(16 * 256 * 4);
  float* bmx  = (float*)alloc(16 * 32 * 4);
  float* bsx  = (float*)alloc(16 * 32 * 4);
  float* bb   = (float*)alloc(16 * 256 * 4);

  prep_w_kernel<<<577, 256, 0, stream>>>(w1, w2, w3, W1Th, W2h, W2l, W3h, W3l, xsum);

  // Gram partials: 16 batches x 8 splits x 2 m-halves (xsum fused, mh==0).
  gram_kernel<<<256, 512, 0, stream>>>(x, Gp, xsum);
  reduce_g_kernel<<<4096, 256, 0, stream>>>(Gp, Gh, Gl);

  // T3 = W3 * G (G symmetric -> TN ok). 64x64 tiles, 256 blocks.
  gemm_small<true, 1><<<dim3(16, 1, 16), 256, 0, stream>>>(
      W3h, W3l, Gh, Gl, 0, 65536, 65536, nullptr, T3h, T3l);
  // Lt = T3 * W2^T  ->  Lt[d][a] = logits[a][d].
  gemm_small<true, 0><<<dim3(16, 1, 16), 256, 0, stream>>>(
      T3h, T3l, W2h, W2l, 65536, 0, 65536, Lb, nullptr, nullptr);

  // softmax: bias prep + pass1 + fused combine/write/bb pass3
  bias_prep_kernel<<<16, 512, 0, stream>>>(w2, w3, xsum, S2, S3);
  softmax_pass1<<<dim3(32, 16), 256, 0, stream>>>(Lb, S2, S3, b2, b3, bmx, bsx);
  softmax_pass3<<<dim3(32, 16), 256, 0, stream>>>(Lb, S2, S3, b2, b3, bmx, bsx,
                                                  b1, WTh, bb);

  // out-chain: Mh = WT*W1T (bf16), out = Mh*X^T + bb
  gemm_small<false, 2><<<dim3(16, 1, 16), 256, 0, stream>>>(
      WTh, nullptr, W1Th, nullptr, 65536, 0, 65536, nullptr, Mh, nullptr);
  gemm_out<<<dim3(32, 1, 16), 256, 0, stream>>>(Mh, x, bb, out);
}